// Round 1
// baseline (1798.317 us; speedup 1.0000x reference)
//
#include <hip/hip_runtime.h>
#include <cmath>

// ---------------- problem constants ----------------
constexpr int BSZ = 16, T = 32, NOBJ = 100;
constexpr int GLOVE = 300, GEMB = 64, ADIM = 10, GCN_DIM = 512, Hh = 512, ASPACE = 6, RES = 512;
constexpr int Bt = BSZ * T;          // 512
constexpr int CHUNK = 128;           // b-chunk for GCN big buffers
constexpr int FUSED_IN = RES + GEMB + ADIM + GCN_DIM; // 1098

// ---------------- generic tiled fp32 GEMM: C = A @ B^T (+bias)(relu) ----------------
// A: [M,K] lda ; B: [N,K] ldb ; C: [M,N] ldc. Optional batch via blockIdx.z with strides.
// SCATTER (Z1 path): row r -> (b=r/100, m=r%100), write C[(b*256+n)*100+m].
constexpr int BM = 64, BN = 64, BK = 16;

template<bool RELU, bool SCATTER>
__global__ __launch_bounds__(256)
void gemm_nt(const float* __restrict__ Ag, int lda, long abs_,
             const float* __restrict__ Bg, int ldb, long bbs_,
             float* __restrict__ Cg, int ldc, long cbs_,
             const float* __restrict__ bias, int M, int N, int K)
{
    const float* A = Ag + (long)blockIdx.z * abs_;
    const float* Bp = Bg + (long)blockIdx.z * bbs_;
    float* C = Cg + (long)blockIdx.z * cbs_;
    const int m0 = blockIdx.y * BM, n0 = blockIdx.x * BN;
    __shared__ float As[BK][BM + 1];
    __shared__ float Bs[BK][BN + 1];
    const int tid = threadIdx.x;
    const int lo = tid * 4;
    const int lm = lo >> 4;      // 0..63 (tile row for loading)
    const int lk = lo & 15;      // 0,4,8,12
    const int row = (tid >> 4) * 4, col = (tid & 15) * 4;
    float acc[4][4] = {};
    for (int k0 = 0; k0 < K; k0 += BK) {
#pragma unroll
        for (int e = 0; e < 4; ++e) {
            int k = lk + e;
            float va = 0.f, vb = 0.f;
            if (k0 + k < K) {
                if (m0 + lm < M) va = A[(long)(m0 + lm) * lda + k0 + k];
                if (n0 + lm < N) vb = Bp[(long)(n0 + lm) * ldb + k0 + k];
            }
            As[k][lm] = va;
            Bs[k][lm] = vb;
        }
        __syncthreads();
#pragma unroll
        for (int k = 0; k < BK; ++k) {
            float a0 = As[k][row], a1 = As[k][row + 1], a2 = As[k][row + 2], a3 = As[k][row + 3];
            float b0 = Bs[k][col], b1 = Bs[k][col + 1], b2 = Bs[k][col + 2], b3 = Bs[k][col + 3];
            acc[0][0] += a0 * b0; acc[0][1] += a0 * b1; acc[0][2] += a0 * b2; acc[0][3] += a0 * b3;
            acc[1][0] += a1 * b0; acc[1][1] += a1 * b1; acc[1][2] += a1 * b2; acc[1][3] += a1 * b3;
            acc[2][0] += a2 * b0; acc[2][1] += a2 * b1; acc[2][2] += a2 * b2; acc[2][3] += a2 * b3;
            acc[3][0] += a3 * b0; acc[3][1] += a3 * b1; acc[3][2] += a3 * b2; acc[3][3] += a3 * b3;
        }
        __syncthreads();
    }
#pragma unroll
    for (int i = 0; i < 4; ++i) {
        int m = m0 + row + i;
        if (m >= M) continue;
#pragma unroll
        for (int j = 0; j < 4; ++j) {
            int n = n0 + col + j;
            if (n >= N) continue;
            float v = acc[i][j];
            if (bias) v += bias[n];
            if (RELU) v = fmaxf(v, 0.f);
            if (SCATTER) {
                int bl = m / 100, mm = m - bl * 100;
                C[((long)(bl * 256 + n)) * 100 + mm] = v;
            } else {
                C[(long)m * ldc + n] = v;
            }
        }
    }
}

// ---------------- small glue kernels ----------------
// Aw = A @ word  (NN, [100,100]@[100,64]) plus rowsum[n] = sum_m A[n,m]
__global__ void k_aw_rowsum(const float* __restrict__ A, const float* __restrict__ word,
                            float* __restrict__ Aw, float* __restrict__ rowsum)
{
    int i = blockIdx.x * 256 + threadIdx.x;
    if (i < 6400) {
        int n = i / 64, k = i % 64;
        float s = 0.f;
        for (int m = 0; m < 100; ++m) s += A[n * 100 + m] * word[m * 64 + k];
        Aw[i] = s;
    } else if (i < 6500) {
        int n = i - 6400;
        float s = 0.f;
        for (int m = 0; m < 100; ++m) s += A[n * 100 + m];
        rowsum[n] = s;
    }
}

// X1[bl,n,k] = relu(rowsum[n]*u[b0+bl,k] + v[n,k]), chunk-local [CHUNK*100,256]
__global__ void k_x1(const float* __restrict__ u, const float* __restrict__ v,
                     const float* __restrict__ rowsum, float* __restrict__ X1, int b0)
{
    long i = (long)blockIdx.x * 256 + threadIdx.x;   // < CHUNK*100*256
    int k = (int)(i & 255);
    long r = i >> 8;
    int n = (int)(r % 100);
    int bl = (int)(r / 100);
    float val = rowsum[n] * u[(long)(b0 + bl) * 256 + k] + v[n * 256 + k];
    X1[i] = fmaxf(val, 0.f);
}

// s[(b0+bl)*100+m] = sum_k X2[bl,m,k]*w2[k]  (one wave per row)
__global__ void k_s(const float* __restrict__ X2, const float* __restrict__ W2,
                    float* __restrict__ s, int b0)
{
    int wave = blockIdx.x * 4 + (threadIdx.x >> 6);  // row within chunk, < CHUNK*100
    int lane = threadIdx.x & 63;
    const float* xr = X2 + (long)wave * 256;
    float acc = 0.f;
#pragma unroll
    for (int k = 0; k < 4; ++k) acc += xr[lane + k * 64] * W2[lane + k * 64];
    for (int off = 32; off > 0; off >>= 1) acc += __shfl_down(acc, off);
    if (lane == 0) {
        int bl = wave / 100, m = wave - bl * 100;
        s[(long)(b0 + bl) * 100 + m] = acc;
    }
}

// fused concat [512,1098]: feats | glove_e | act_e | gcn_e
__global__ void k_fused(const float* __restrict__ feats, const float* __restrict__ ge,
                        const float* __restrict__ ae, const float* __restrict__ gcn,
                        float* __restrict__ fused)
{
    int i = blockIdx.x * 256 + threadIdx.x;       // < 512*1098
    int b = i / FUSED_IN, c = i - b * FUSED_IN;
    float v;
    if (c < 512) v = feats[(long)b * 512 + c];
    else if (c < 576) v = ge[(long)b * 64 + (c - 512)];
    else if (c < 586) v = ae[(long)b * 10 + (c - 576)];
    else v = gcn[(long)b * 512 + (c - 586)];
    fused[i] = v;
}

__global__ void k_bsum(const float* __restrict__ bih, const float* __restrict__ bhh,
                       float* __restrict__ bsum)
{
    int i = blockIdx.x * 256 + threadIdx.x;
    if (i < 2048) bsum[i] = bih[i] + bhh[i];
}

// WhhT2[h*2048 + jh*4 + g] = Whh[(g*512+jh)*512 + h]
__global__ void k_whht2(const float* __restrict__ Whh, float* __restrict__ WhhT2)
{
    int i = blockIdx.x * 256 + threadIdx.x;       // < 1048576
    int hh = i >> 11;
    int rem = i & 2047;
    int jh = rem >> 2, g = rem & 3;
    WhhT2[i] = Whh[(long)(g * 512 + jh) * 512 + hh];
}

__global__ void k_zero(float* __restrict__ p, int n)
{
    int i = blockIdx.x * 256 + threadIdx.x;
    if (i < n) p[i] = 0.f;
}

__device__ __forceinline__ float sigf(float x) { return 1.f / (1.f + __expf(-x)); }

// One LSTM time step. 32 blocks x 256 threads; thread -> (b = tid/16, jh = bx*16 + tid%16).
__global__ __launch_bounds__(256)
void lstm_step(const float* __restrict__ xWih,    // [512,2048] incl. biases
               const float* __restrict__ WhhT2,   // [512][2048] gate-interleaved
               const float* __restrict__ hPrev, const float* __restrict__ cPrev,
               float* __restrict__ hNext, float* __restrict__ cNext,
               float* __restrict__ sf, int t)
{
    __shared__ float hlds[BSZ * Hh];               // 32 KB
    const int tid = threadIdx.x;
    for (int i = tid; i < BSZ * Hh; i += 256) hlds[i] = hPrev[i];
    __syncthreads();
    const int jh = blockIdx.x * 16 + (tid & 15);
    const int b = tid >> 4;
    float ai = 0.f, af = 0.f, ag = 0.f, ao = 0.f;
    const float* hb = &hlds[b * Hh];
    const float4* wbase = (const float4*)WhhT2;
#pragma unroll 4
    for (int hh = 0; hh < Hh; ++hh) {
        float4 w = wbase[(long)hh * 512 + jh];
        float hp = hb[hh];
        ai = fmaf(w.x, hp, ai);
        af = fmaf(w.y, hp, af);
        ag = fmaf(w.z, hp, ag);
        ao = fmaf(w.w, hp, ao);
    }
    const float* xw = xWih + (long)(b * T + t) * 2048;
    float gi = xw[jh] + ai;
    float gf = xw[512 + jh] + af;
    float gg = xw[1024 + jh] + ag;
    float go = xw[1536 + jh] + ao;
    float cp = cPrev[b * Hh + jh];
    float cn = sigf(gf) * cp + sigf(gi) * tanhf(gg);
    float hn = sigf(go) * tanhf(cn);
    cNext[b * Hh + jh] = cn;
    hNext[b * Hh + jh] = hn;
    sf[(long)(b * T + t) * Hh + jh] = hn;
}

// copy final h,c into output
__global__ void k_copy_hc(const float* __restrict__ h, const float* __restrict__ c,
                          float* __restrict__ out)
{
    int i = blockIdx.x * 256 + threadIdx.x;        // < 8192
    out[3584 + i] = h[i];
    out[11776 + i] = c[i];
}

// ---------------- host ----------------
static inline void gemm(hipStream_t st, const float* A, int lda, long abs_,
                        const float* Bp, int ldb, long bbs, float* C, int ldc, long cbs,
                        const float* bias, int M, int N, int K, int batch,
                        bool relu, bool scatter = false)
{
    dim3 g((N + BN - 1) / BN, (M + BM - 1) / BM, batch), blk(256);
    if (scatter)
        hipLaunchKernelGGL((gemm_nt<false, true>), g, blk, 0, st, A, lda, abs_, Bp, ldb, bbs, C, ldc, cbs, bias, M, N, K);
    else if (relu)
        hipLaunchKernelGGL((gemm_nt<true, false>), g, blk, 0, st, A, lda, abs_, Bp, ldb, bbs, C, ldc, cbs, bias, M, N, K);
    else
        hipLaunchKernelGGL((gemm_nt<false, false>), g, blk, 0, st, A, lda, abs_, Bp, ldb, bbs, C, ldc, cbs, bias, M, N, K);
}

extern "C" void kernel_launch(void* const* d_in, const int* in_sizes, int n_in,
                              void* d_out, int out_size, void* d_ws, size_t ws_size,
                              hipStream_t stream)
{
    const float* target = (const float*)d_in[0];
    const float* input_ = (const float*)d_in[1];
    const float* aprob  = (const float*)d_in[2];
    const float* Adj    = (const float*)d_in[3];
    const float* aglove = (const float*)d_in[4];
    const float* Wword  = (const float*)d_in[5];
    const float* bword  = (const float*)d_in[6];
    const float* Wg     = (const float*)d_in[7];
    const float* bg     = (const float*)d_in[8];
    const float* Wa     = (const float*)d_in[9];
    const float* ba     = (const float*)d_in[10];
    const float* W0     = (const float*)d_in[11];
    const float* W1     = (const float*)d_in[12];
    const float* W2     = (const float*)d_in[13];
    const float* Wfm    = (const float*)d_in[14];
    const float* bfm    = (const float*)d_in[15];
    const float* Wf     = (const float*)d_in[16];
    const float* bf     = (const float*)d_in[17];
    const float* Wih    = (const float*)d_in[18];
    const float* Whh    = (const float*)d_in[19];
    const float* bih    = (const float*)d_in[20];
    const float* bhh    = (const float*)d_in[21];
    const float* Wa1    = (const float*)d_in[22];
    const float* ba1    = (const float*)d_in[23];
    const float* Wa2    = (const float*)d_in[24];
    const float* ba2    = (const float*)d_in[25];
    const float* Wc1    = (const float*)d_in[26];
    const float* bc1    = (const float*)d_in[27];
    const float* Wc2    = (const float*)d_in[28];
    const float* bc2    = (const float*)d_in[29];

    float* ws = (float*)d_ws;
    float* out = (float*)d_out;

    // workspace allocator (float offsets, 256-float aligned)
    size_t off = 0;
    auto alloc = [&](size_t n) { size_t r = off; off += (n + 255) & ~(size_t)255; return r; };
    float* glove_e = ws + alloc(512 * 64);
    float* act_e   = ws + alloc(512 * 10);
    float* u       = ws + alloc(512 * 256);
    float* word    = ws + alloc(100 * 64);
    float* Aw      = ws + alloc(100 * 64);
    float* rowsum  = ws + alloc(128);
    float* v       = ws + alloc(100 * 256);
    float* gcn_e   = ws + alloc(512 * 512);
    float* fused   = ws + alloc(512 * FUSED_IN);
    float* outf    = ws + alloc(512 * 512);
    float* bsum    = ws + alloc(2048);
    float* xWih    = ws + alloc((size_t)512 * 2048);
    float* WhhT2   = ws + alloc((size_t)512 * 2048);
    float* hA      = ws + alloc(BSZ * Hh);
    float* cA      = ws + alloc(BSZ * Hh);
    float* hB      = ws + alloc(BSZ * Hh);
    float* cB      = ws + alloc(BSZ * Hh);
    float* sf      = ws + alloc(512 * 512);
    float* ah      = ws + alloc(512 * 128);
    float* ch      = ws + alloc(512 * 128);
    float* s_buf   = ws + alloc(512 * 100);
    float* x3      = ws + alloc(512 * 100);
    float* X1      = ws + alloc((size_t)CHUNK * 100 * 256);
    float* Z1t     = ws + alloc((size_t)CHUNK * 256 * 100);
    float* X2      = ws + alloc((size_t)CHUNK * 100 * 256);
    (void)ws_size; (void)in_sizes; (void)n_in; (void)out_size;

    const float* feats = input_; // [512,512] (trailing 1x1 squeezed)

    // --- embeddings & separable precomputes ---
    gemm(stream, target, GLOVE, 0, Wg, GLOVE, 0, glove_e, 64, 0, bg, 512, 64, GLOVE, 1, true);
    gemm(stream, aprob, ASPACE, 0, Wa, ASPACE, 0, act_e, 10, 0, ba, 512, 10, ASPACE, 1, true);
    gemm(stream, feats, 512, 0, W0, 576, 0, u, 256, 0, nullptr, 512, 256, 512, 1, false);
    gemm(stream, aglove, GLOVE, 0, Wword, GLOVE, 0, word, 64, 0, bword, 100, 64, GLOVE, 1, false);
    hipLaunchKernelGGL(k_aw_rowsum, dim3(26), dim3(256), 0, stream, Adj, word, Aw, rowsum);
    gemm(stream, Aw, 64, 0, W0 + 512, 576, 0, v, 256, 0, nullptr, 100, 256, 64, 1, false);

    // --- GCN chunks ---
    for (int cc = 0; cc < Bt / CHUNK; ++cc) {
        int b0 = cc * CHUNK;
        hipLaunchKernelGGL(k_x1, dim3(CHUNK * 100), dim3(256), 0, stream, u, v, rowsum, X1, b0);
        // Z1 = X1 @ W1^T, scattered to per-b transposed layout [b][256][100]
        gemm(stream, X1, 256, 0, W1, 256, 0, Z1t, 0, 0, nullptr, CHUNK * 100, 256, 256, 1, false, true);
        // X2[b] = relu(Adj @ Z1[b])  -> NT with Bt = Z1t[b] ([256,100])
        gemm(stream, Adj, 100, 0, Z1t, 100, 25600, X2, 256, 25600, nullptr, 100, 256, 100, CHUNK, true);
        hipLaunchKernelGGL(k_s, dim3(CHUNK * 100 / 4), dim3(256), 0, stream, X2, W2, s_buf, b0);
    }
    // x3 = relu(s @ Adj^T) : [512,100]
    gemm(stream, s_buf, 100, 0, Adj, 100, 0, x3, 100, 0, nullptr, 512, 100, 100, 1, true);
    // gcn_e = x3 @ Wfm^T + bfm : [512,512]
    gemm(stream, x3, 100, 0, Wfm, 100, 0, gcn_e, 512, 0, bfm, 512, 512, 100, 1, false);

    // --- fuse + trunk ---
    hipLaunchKernelGGL(k_fused, dim3(512 * FUSED_IN / 256), dim3(256), 0, stream, feats, glove_e, act_e, gcn_e, fused);
    gemm(stream, fused, FUSED_IN, 0, Wf, FUSED_IN, 0, outf, 512, 0, bf, 512, 512, FUSED_IN, 1, true);

    // --- LSTM precompute ---
    hipLaunchKernelGGL(k_bsum, dim3(8), dim3(256), 0, stream, bih, bhh, bsum);
    gemm(stream, outf, 512, 0, Wih, 512, 0, xWih, 2048, 0, bsum, 512, 2048, 512, 1, false);
    hipLaunchKernelGGL(k_whht2, dim3(4096), dim3(256), 0, stream, Whh, WhhT2);
    hipLaunchKernelGGL(k_zero, dim3((4 * BSZ * Hh + 255) / 256), dim3(256), 0, stream, hA, 4 * BSZ * Hh);
    // NOTE: hA,cA,hB,cB are contiguous by the allocator (each 8192, 256-aligned)

    // --- LSTM recurrence: 32 steps, ping-pong h/c buffers ---
    for (int t = 0; t < T; ++t) {
        const float* hp = (t & 1) ? hB : hA;
        const float* cp = (t & 1) ? cB : cA;
        float* hn = (t & 1) ? hA : hB;
        float* cn = (t & 1) ? cA : cB;
        hipLaunchKernelGGL(lstm_step, dim3(32), dim3(256), 0, stream, xWih, WhhT2, hp, cp, hn, cn, sf, t);
    }
    // after t=31 (odd), final state is in hA/cA

    // --- heads ---
    gemm(stream, sf, 512, 0, Wa1, 512, 0, ah, 128, 0, ba1, 512, 128, 512, 1, true);
    gemm(stream, ah, 128, 0, Wa2, 128, 0, out, 6, 0, ba2, 512, 6, 128, 1, true);
    gemm(stream, sf, 512, 0, Wc1, 512, 0, ch, 128, 0, bc1, 512, 128, 512, 1, true);
    gemm(stream, ch, 128, 0, Wc2, 128, 0, out + 3072, 1, 0, bc2, 512, 1, 128, 1, true);
    hipLaunchKernelGGL(k_copy_hc, dim3(32), dim3(256), 0, stream, hA, cA, out);
}

// Round 2
// 1790.615 us; speedup vs baseline: 1.0043x; 1.0043x over previous
//
#include <hip/hip_runtime.h>
#include <cmath>

// ---------------- problem constants ----------------
constexpr int BSZ = 16, T = 32, NOBJ = 100;
constexpr int GLOVE = 300, GEMB = 64, ADIM = 10, GCN_DIM = 512, Hh = 512, ASPACE = 6, RES = 512;
constexpr int Bt = BSZ * T;          // 512
constexpr int CHUNK = 128;           // b-chunk for GCN big buffers
constexpr int FUSED_IN = RES + GEMB + ADIM + GCN_DIM; // 1098

// ---------------- generic tiled fp32 GEMM: C = A @ B^T (+bias)(relu) ----------------
// A: [M,K] lda ; B: [N,K] ldb ; C: [M,N] ldc. Optional batch via blockIdx.z with strides.
// SCATTER (Z1 path): row r -> (b=r/100, m=r%100), write C[(b*256+n)*100+m].
constexpr int BM = 64, BN = 64, BK = 16;

template<bool RELU, bool SCATTER>
__global__ __launch_bounds__(256)
void gemm_nt(const float* __restrict__ Ag, int lda, long abs_,
             const float* __restrict__ Bg, int ldb, long bbs_,
             float* __restrict__ Cg, int ldc, long cbs_,
             const float* __restrict__ bias, int M, int N, int K)
{
    const float* A = Ag + (long)blockIdx.z * abs_;
    const float* Bp = Bg + (long)blockIdx.z * bbs_;
    float* C = Cg + (long)blockIdx.z * cbs_;
    const int m0 = blockIdx.y * BM, n0 = blockIdx.x * BN;
    __shared__ float As[BK][BM + 1];
    __shared__ float Bs[BK][BN + 1];
    const int tid = threadIdx.x;
    const int lo = tid * 4;
    const int lm = lo >> 4;      // 0..63 (tile row for loading)
    const int lk = lo & 15;      // 0,4,8,12
    const int row = (tid >> 4) * 4, col = (tid & 15) * 4;
    float acc[4][4] = {};
    for (int k0 = 0; k0 < K; k0 += BK) {
#pragma unroll
        for (int e = 0; e < 4; ++e) {
            int k = lk + e;
            float va = 0.f, vb = 0.f;
            if (k0 + k < K) {
                if (m0 + lm < M) va = A[(long)(m0 + lm) * lda + k0 + k];
                if (n0 + lm < N) vb = Bp[(long)(n0 + lm) * ldb + k0 + k];
            }
            As[k][lm] = va;
            Bs[k][lm] = vb;
        }
        __syncthreads();
#pragma unroll
        for (int k = 0; k < BK; ++k) {
            float a0 = As[k][row], a1 = As[k][row + 1], a2 = As[k][row + 2], a3 = As[k][row + 3];
            float b0 = Bs[k][col], b1 = Bs[k][col + 1], b2 = Bs[k][col + 2], b3 = Bs[k][col + 3];
            acc[0][0] += a0 * b0; acc[0][1] += a0 * b1; acc[0][2] += a0 * b2; acc[0][3] += a0 * b3;
            acc[1][0] += a1 * b0; acc[1][1] += a1 * b1; acc[1][2] += a1 * b2; acc[1][3] += a1 * b3;
            acc[2][0] += a2 * b0; acc[2][1] += a2 * b1; acc[2][2] += a2 * b2; acc[2][3] += a2 * b3;
            acc[3][0] += a3 * b0; acc[3][1] += a3 * b1; acc[3][2] += a3 * b2; acc[3][3] += a3 * b3;
        }
        __syncthreads();
    }
#pragma unroll
    for (int i = 0; i < 4; ++i) {
        int m = m0 + row + i;
        if (m >= M) continue;
#pragma unroll
        for (int j = 0; j < 4; ++j) {
            int n = n0 + col + j;
            if (n >= N) continue;
            float v = acc[i][j];
            if (bias) v += bias[n];
            if (RELU) v = fmaxf(v, 0.f);
            if (SCATTER) {
                int bl = m / 100, mm = m - bl * 100;
                C[((long)(bl * 256 + n)) * 100 + mm] = v;
            } else {
                C[(long)m * ldc + n] = v;
            }
        }
    }
}

// ---------------- small glue kernels ----------------
// Aw = A @ word  (NN, [100,100]@[100,64]) plus rowsum[n] = sum_m A[n,m]
__global__ void k_aw_rowsum(const float* __restrict__ A, const float* __restrict__ word,
                            float* __restrict__ Aw, float* __restrict__ rowsum)
{
    int i = blockIdx.x * 256 + threadIdx.x;
    if (i < 6400) {
        int n = i / 64, k = i % 64;
        float s = 0.f;
        for (int m = 0; m < 100; ++m) s += A[n * 100 + m] * word[m * 64 + k];
        Aw[i] = s;
    } else if (i < 6500) {
        int n = i - 6400;
        float s = 0.f;
        for (int m = 0; m < 100; ++m) s += A[n * 100 + m];
        rowsum[n] = s;
    }
}

// X1[bl,n,k] = relu(rowsum[n]*u[b0+bl,k] + v[n,k]), chunk-local [CHUNK*100,256]
__global__ void k_x1(const float* __restrict__ u, const float* __restrict__ v,
                     const float* __restrict__ rowsum, float* __restrict__ X1, int b0)
{
    long i = (long)blockIdx.x * 256 + threadIdx.x;   // < CHUNK*100*256
    int k = (int)(i & 255);
    long r = i >> 8;
    int n = (int)(r % 100);
    int bl = (int)(r / 100);
    float val = rowsum[n] * u[(long)(b0 + bl) * 256 + k] + v[n * 256 + k];
    X1[i] = fmaxf(val, 0.f);
}

// s[(b0+bl)*100+m] = sum_k X2[bl,m,k]*w2[k]  (one wave per row)
__global__ void k_s(const float* __restrict__ X2, const float* __restrict__ W2,
                    float* __restrict__ s, int b0)
{
    int wave = blockIdx.x * 4 + (threadIdx.x >> 6);  // row within chunk, < CHUNK*100
    int lane = threadIdx.x & 63;
    const float* xr = X2 + (long)wave * 256;
    float acc = 0.f;
#pragma unroll
    for (int k = 0; k < 4; ++k) acc += xr[lane + k * 64] * W2[lane + k * 64];
    for (int off = 32; off > 0; off >>= 1) acc += __shfl_down(acc, off);
    if (lane == 0) {
        int bl = wave / 100, m = wave - bl * 100;
        s[(long)(b0 + bl) * 100 + m] = acc;
    }
}

// fused concat [512,1098]: feats | glove_e | act_e | gcn_e
__global__ void k_fused(const float* __restrict__ feats, const float* __restrict__ ge,
                        const float* __restrict__ ae, const float* __restrict__ gcn,
                        float* __restrict__ fused)
{
    int i = blockIdx.x * 256 + threadIdx.x;       // < 512*1098
    int b = i / FUSED_IN, c = i - b * FUSED_IN;
    float v;
    if (c < 512) v = feats[(long)b * 512 + c];
    else if (c < 576) v = ge[(long)b * 64 + (c - 512)];
    else if (c < 586) v = ae[(long)b * 10 + (c - 576)];
    else v = gcn[(long)b * 512 + (c - 586)];
    fused[i] = v;
}

__global__ void k_bsum(const float* __restrict__ bih, const float* __restrict__ bhh,
                       float* __restrict__ bsum)
{
    int i = blockIdx.x * 256 + threadIdx.x;
    if (i < 2048) bsum[i] = bih[i] + bhh[i];
}

// WhhT2[h*2048 + jh*4 + g] = Whh[(g*512+jh)*512 + h]
__global__ void k_whht2(const float* __restrict__ Whh, float* __restrict__ WhhT2)
{
    int i = blockIdx.x * 256 + threadIdx.x;       // < 1048576
    int hh = i >> 11;
    int rem = i & 2047;
    int jh = rem >> 2, g = rem & 3;
    WhhT2[i] = Whh[(long)(g * 512 + jh) * 512 + hh];
}

__global__ void k_zero(float* __restrict__ p, int n)
{
    int i = blockIdx.x * 256 + threadIdx.x;
    if (i < n) p[i] = 0.f;
}

__device__ __forceinline__ float sigf(float x) { return 1.f / (1.f + __expf(-x)); }

// One LSTM time step. 32 blocks x 256 threads; thread -> (b = tid/16, jh = bx*16 + tid%16).
__global__ __launch_bounds__(256)
void lstm_step(const float* __restrict__ xWih,    // [512,2048] incl. biases
               const float* __restrict__ WhhT2,   // [512][2048] gate-interleaved
               const float* __restrict__ hPrev, const float* __restrict__ cPrev,
               float* __restrict__ hNext, float* __restrict__ cNext,
               float* __restrict__ sf, int t)
{
    __shared__ float hlds[BSZ * Hh];               // 32 KB
    const int tid = threadIdx.x;
    for (int i = tid; i < BSZ * Hh; i += 256) hlds[i] = hPrev[i];
    __syncthreads();
    const int jh = blockIdx.x * 16 + (tid & 15);
    const int b = tid >> 4;
    float ai = 0.f, af = 0.f, ag = 0.f, ao = 0.f;
    const float* hb = &hlds[b * Hh];
    const float4* wbase = (const float4*)WhhT2;
#pragma unroll 4
    for (int hh = 0; hh < Hh; ++hh) {
        float4 w = wbase[(long)hh * 512 + jh];
        float hp = hb[hh];
        ai = fmaf(w.x, hp, ai);
        af = fmaf(w.y, hp, af);
        ag = fmaf(w.z, hp, ag);
        ao = fmaf(w.w, hp, ao);
    }
    const float* xw = xWih + (long)(b * T + t) * 2048;
    float gi = xw[jh] + ai;
    float gf = xw[512 + jh] + af;
    float gg = xw[1024 + jh] + ag;
    float go = xw[1536 + jh] + ao;
    float cp = cPrev[b * Hh + jh];
    float cn = sigf(gf) * cp + sigf(gi) * tanhf(gg);
    float hn = sigf(go) * tanhf(cn);
    cNext[b * Hh + jh] = cn;
    hNext[b * Hh + jh] = hn;
    sf[(long)(b * T + t) * Hh + jh] = hn;
}

// copy final h,c into output
__global__ void k_copy_hc(const float* __restrict__ h, const float* __restrict__ c,
                          float* __restrict__ out)
{
    int i = blockIdx.x * 256 + threadIdx.x;        // < 8192
    out[3584 + i] = h[i];
    out[11776 + i] = c[i];
}

// ---------------- host ----------------
static inline void gemm(hipStream_t st, const float* A, int lda, long abs_,
                        const float* Bp, int ldb, long bbs, float* C, int ldc, long cbs,
                        const float* bias, int M, int N, int K, int batch,
                        bool relu, bool scatter = false)
{
    dim3 g((N + BN - 1) / BN, (M + BM - 1) / BM, batch), blk(256);
    if (scatter)
        hipLaunchKernelGGL((gemm_nt<false, true>), g, blk, 0, st, A, lda, abs_, Bp, ldb, bbs, C, ldc, cbs, bias, M, N, K);
    else if (relu)
        hipLaunchKernelGGL((gemm_nt<true, false>), g, blk, 0, st, A, lda, abs_, Bp, ldb, bbs, C, ldc, cbs, bias, M, N, K);
    else
        hipLaunchKernelGGL((gemm_nt<false, false>), g, blk, 0, st, A, lda, abs_, Bp, ldb, bbs, C, ldc, cbs, bias, M, N, K);
}

extern "C" void kernel_launch(void* const* d_in, const int* in_sizes, int n_in,
                              void* d_out, int out_size, void* d_ws, size_t ws_size,
                              hipStream_t stream)
{
    const float* target = (const float*)d_in[0];
    const float* input_ = (const float*)d_in[1];
    const float* aprob  = (const float*)d_in[2];
    const float* Adj    = (const float*)d_in[3];
    const float* aglove = (const float*)d_in[4];
    const float* Wword  = (const float*)d_in[5];
    const float* bword  = (const float*)d_in[6];
    const float* Wg     = (const float*)d_in[7];
    const float* bg     = (const float*)d_in[8];
    const float* Wa     = (const float*)d_in[9];
    const float* ba     = (const float*)d_in[10];
    const float* W0     = (const float*)d_in[11];
    const float* W1     = (const float*)d_in[12];
    const float* W2     = (const float*)d_in[13];
    const float* Wfm    = (const float*)d_in[14];
    const float* bfm    = (const float*)d_in[15];
    const float* Wf     = (const float*)d_in[16];
    const float* bf     = (const float*)d_in[17];
    const float* Wih    = (const float*)d_in[18];
    const float* Whh    = (const float*)d_in[19];
    const float* bih    = (const float*)d_in[20];
    const float* bhh    = (const float*)d_in[21];
    const float* Wa1    = (const float*)d_in[22];
    const float* ba1    = (const float*)d_in[23];
    const float* Wa2    = (const float*)d_in[24];
    const float* ba2    = (const float*)d_in[25];
    const float* Wc1    = (const float*)d_in[26];
    const float* bc1    = (const float*)d_in[27];
    const float* Wc2    = (const float*)d_in[28];
    const float* bc2    = (const float*)d_in[29];

    float* ws = (float*)d_ws;
    float* out = (float*)d_out;

    // workspace allocator (float offsets, 256-float aligned)
    size_t off = 0;
    auto alloc = [&](size_t n) { size_t r = off; off += (n + 255) & ~(size_t)255; return r; };
    float* glove_e = ws + alloc(512 * 64);
    float* act_e   = ws + alloc(512 * 10);
    float* u       = ws + alloc(512 * 256);
    float* word    = ws + alloc(100 * 64);
    float* Aw      = ws + alloc(100 * 64);
    float* rowsum  = ws + alloc(128);
    float* v       = ws + alloc(100 * 256);
    float* gcn_e   = ws + alloc(512 * 512);
    float* fused   = ws + alloc(512 * FUSED_IN);
    float* outf    = ws + alloc(512 * 512);
    float* bsum    = ws + alloc(2048);
    float* xWih    = ws + alloc((size_t)512 * 2048);
    float* WhhT2   = ws + alloc((size_t)512 * 2048);
    float* hA      = ws + alloc(BSZ * Hh);
    float* cA      = ws + alloc(BSZ * Hh);
    float* hB      = ws + alloc(BSZ * Hh);
    float* cB      = ws + alloc(BSZ * Hh);
    float* sf      = ws + alloc(512 * 512);
    float* ah      = ws + alloc(512 * 128);
    float* ch      = ws + alloc(512 * 128);
    float* s_buf   = ws + alloc(512 * 100);
    float* x3      = ws + alloc(512 * 100);
    float* X1      = ws + alloc((size_t)CHUNK * 100 * 256);
    float* Z1t     = ws + alloc((size_t)CHUNK * 256 * 100);
    float* X2      = ws + alloc((size_t)CHUNK * 100 * 256);
    (void)ws_size; (void)in_sizes; (void)n_in; (void)out_size;

    const float* feats = input_; // [512,512] (trailing 1x1 squeezed)

    // --- embeddings & separable precomputes ---
    gemm(stream, target, GLOVE, 0, Wg, GLOVE, 0, glove_e, 64, 0, bg, 512, 64, GLOVE, 1, true);
    gemm(stream, aprob, ASPACE, 0, Wa, ASPACE, 0, act_e, 10, 0, ba, 512, 10, ASPACE, 1, true);
    gemm(stream, feats, 512, 0, W0, 576, 0, u, 256, 0, nullptr, 512, 256, 512, 1, false);
    gemm(stream, aglove, GLOVE, 0, Wword, GLOVE, 0, word, 64, 0, bword, 100, 64, GLOVE, 1, false);
    hipLaunchKernelGGL(k_aw_rowsum, dim3(26), dim3(256), 0, stream, Adj, word, Aw, rowsum);
    gemm(stream, Aw, 64, 0, W0 + 512, 576, 0, v, 256, 0, nullptr, 100, 256, 64, 1, false);

    // --- GCN chunks ---
    for (int cc = 0; cc < Bt / CHUNK; ++cc) {
        int b0 = cc * CHUNK;
        hipLaunchKernelGGL(k_x1, dim3(CHUNK * 100), dim3(256), 0, stream, u, v, rowsum, X1, b0);
        // Z1 = X1 @ W1^T, scattered to per-b transposed layout [b][256][100]
        gemm(stream, X1, 256, 0, W1, 256, 0, Z1t, 0, 0, nullptr, CHUNK * 100, 256, 256, 1, false, true);
        // X2[b] = relu(Adj @ Z1[b])  -> NT with Bt = Z1t[b] ([256,100])
        gemm(stream, Adj, 100, 0, Z1t, 100, 25600, X2, 256, 25600, nullptr, 100, 256, 100, CHUNK, true);
        hipLaunchKernelGGL(k_s, dim3(CHUNK * 100 / 4), dim3(256), 0, stream, X2, W2, s_buf, b0);
    }
    // x3 = relu(s @ Adj^T) : [512,100]
    gemm(stream, s_buf, 100, 0, Adj, 100, 0, x3, 100, 0, nullptr, 512, 100, 100, 1, true);
    // gcn_e = x3 @ Wfm^T + bfm : [512,512]
    gemm(stream, x3, 100, 0, Wfm, 100, 0, gcn_e, 512, 0, bfm, 512, 512, 100, 1, false);

    // --- fuse + trunk ---
    hipLaunchKernelGGL(k_fused, dim3(512 * FUSED_IN / 256), dim3(256), 0, stream, feats, glove_e, act_e, gcn_e, fused);
    gemm(stream, fused, FUSED_IN, 0, Wf, FUSED_IN, 0, outf, 512, 0, bf, 512, 512, FUSED_IN, 1, true);

    // --- LSTM precompute ---
    hipLaunchKernelGGL(k_bsum, dim3(8), dim3(256), 0, stream, bih, bhh, bsum);
    gemm(stream, outf, 512, 0, Wih, 512, 0, xWih, 2048, 0, bsum, 512, 2048, 512, 1, false);
    hipLaunchKernelGGL(k_whht2, dim3(4096), dim3(256), 0, stream, Whh, WhhT2);
    hipLaunchKernelGGL(k_zero, dim3((4 * BSZ * Hh + 255) / 256), dim3(256), 0, stream, hA, 4 * BSZ * Hh);
    // NOTE: hA,cA,hB,cB are contiguous by the allocator (each 8192, 256-aligned)

    // --- LSTM recurrence: 32 steps, ping-pong h/c buffers ---
    for (int t = 0; t < T; ++t) {
        const float* hp = (t & 1) ? hB : hA;
        const float* cp = (t & 1) ? cB : cA;
        float* hn = (t & 1) ? hA : hB;
        float* cn = (t & 1) ? cA : cB;
        hipLaunchKernelGGL(lstm_step, dim3(32), dim3(256), 0, stream, xWih, WhhT2, hp, cp, hn, cn, sf, t);
    }
    // after t=31 (odd), final state is in hA/cA

    // --- heads ---
    gemm(stream, sf, 512, 0, Wa1, 512, 0, ah, 128, 0, ba1, 512, 128, 512, 1, true);
    gemm(stream, ah, 128, 0, Wa2, 128, 0, out, 6, 0, ba2, 512, 6, 128, 1, true);
    gemm(stream, sf, 512, 0, Wc1, 512, 0, ch, 128, 0, bc1, 512, 128, 512, 1, true);
    gemm(stream, ch, 128, 0, Wc2, 128, 0, out + 3072, 1, 0, bc2, 512, 1, 128, 1, true);
    hipLaunchKernelGGL(k_copy_hc, dim3(32), dim3(256), 0, stream, hA, cA, out);
}

// Round 3
// 1506.851 us; speedup vs baseline: 1.1934x; 1.1883x over previous
//
#include <hip/hip_runtime.h>
#include <cmath>

// ---------------- problem constants ----------------
constexpr int BSZ = 16, T = 32, NOBJ = 100;
constexpr int GLOVE = 300, GEMB = 64, ADIM = 10, GCN_DIM = 512, Hh = 512, ASPACE = 6, RES = 512;
constexpr int Bt = BSZ * T;          // 512
constexpr int FUSED_IN = RES + GEMB + ADIM + GCN_DIM; // 1098

// ---------------- generic tiled fp32 GEMM: C = A @ B^T (+bias)(relu) ----------------
constexpr int BM = 64, BN = 64, BK = 16;

template<bool RELU>
__global__ __launch_bounds__(256)
void gemm_nt(const float* __restrict__ Ag, int lda, long abs_,
             const float* __restrict__ Bg, int ldb, long bbs_,
             float* __restrict__ Cg, int ldc, long cbs_,
             const float* __restrict__ bias, int M, int N, int K)
{
    const float* A = Ag + (long)blockIdx.z * abs_;
    const float* Bp = Bg + (long)blockIdx.z * bbs_;
    float* C = Cg + (long)blockIdx.z * cbs_;
    const int m0 = blockIdx.y * BM, n0 = blockIdx.x * BN;
    __shared__ float As[BK][BM + 1];
    __shared__ float Bs[BK][BN + 1];
    const int tid = threadIdx.x;
    const int lo = tid * 4;
    const int lm = lo >> 4;      // 0..63 (tile row for loading)
    const int lk = lo & 15;      // 0,4,8,12
    const int row = (tid >> 4) * 4, col = (tid & 15) * 4;
    float acc[4][4] = {};
    for (int k0 = 0; k0 < K; k0 += BK) {
#pragma unroll
        for (int e = 0; e < 4; ++e) {
            int k = lk + e;
            float va = 0.f, vb = 0.f;
            if (k0 + k < K) {
                if (m0 + lm < M) va = A[(long)(m0 + lm) * lda + k0 + k];
                if (n0 + lm < N) vb = Bp[(long)(n0 + lm) * ldb + k0 + k];
            }
            As[k][lm] = va;
            Bs[k][lm] = vb;
        }
        __syncthreads();
#pragma unroll
        for (int k = 0; k < BK; ++k) {
            float a0 = As[k][row], a1 = As[k][row + 1], a2 = As[k][row + 2], a3 = As[k][row + 3];
            float b0 = Bs[k][col], b1 = Bs[k][col + 1], b2 = Bs[k][col + 2], b3 = Bs[k][col + 3];
            acc[0][0] += a0 * b0; acc[0][1] += a0 * b1; acc[0][2] += a0 * b2; acc[0][3] += a0 * b3;
            acc[1][0] += a1 * b0; acc[1][1] += a1 * b1; acc[1][2] += a1 * b2; acc[1][3] += a1 * b3;
            acc[2][0] += a2 * b0; acc[2][1] += a2 * b1; acc[2][2] += a2 * b2; acc[2][3] += a2 * b3;
            acc[3][0] += a3 * b0; acc[3][1] += a3 * b1; acc[3][2] += a3 * b2; acc[3][3] += a3 * b3;
        }
        __syncthreads();
    }
#pragma unroll
    for (int i = 0; i < 4; ++i) {
        int m = m0 + row + i;
        if (m >= M) continue;
#pragma unroll
        for (int j = 0; j < 4; ++j) {
            int n = n0 + col + j;
            if (n >= N) continue;
            float v = acc[i][j];
            if (bias) v += bias[n];
            if (RELU) v = fmaxf(v, 0.f);
            C[(long)m * ldc + n] = v;
        }
    }
}

// ---------------- fused GCN middle ----------------
// One block per b (512 blocks, 256 threads). Lane owns output column j = tid.
// z[100] registers = Z1[:, j] ; A (100x100) resident in LDS.
constexpr int KT = 16;     // k-tile for x1 staging
constexpr int PAD = 104;   // n-axis stride (floats), 16B-aligned rows

__global__ __launch_bounds__(256, 2)
void gcn_fused(const float* __restrict__ u,      // [512,256] feats@W0a^T
               const float* __restrict__ v,      // [100,256] Aw@W0b^T
               const float* __restrict__ rowsum, // [100]
               const float* __restrict__ A,      // [100,100]
               const float* __restrict__ W1T,    // [256,256], W1T[k][j] = W1[j][k]
               const float* __restrict__ w2,     // [256]
               float* __restrict__ x3)           // [512,100] = relu(A @ s_b)
{
    __shared__ float A_lds[100 * PAD];   // 41.6 KB
    __shared__ float x1t[KT * PAD];      // 6.7 KB, x1t[k][n]
    __shared__ float u_lds[256];
    __shared__ float rs_lds[100];
    __shared__ float spart[4 * 100];
    __shared__ float s_lds[100];

    const int b = blockIdx.x;
    const int tid = threadIdx.x;
    const int lane = tid & 63, wave = tid >> 6;
    const int j = tid;                    // output column 0..255

    // ---- stage A, u, rowsum ----
    for (int r = wave; r < 100; r += 4)
        for (int c = lane; c < 100; c += 64)
            A_lds[r * PAD + c] = A[r * 100 + c];
    u_lds[tid] = u[(long)b * 256 + tid];
    if (tid < 100) rs_lds[tid] = rowsum[tid];
    const float w2j = w2[j];

    float z[100];
#pragma unroll
    for (int n = 0; n < 100; ++n) z[n] = 0.f;

    // ---- phase 1: z[n] = Z1[n,j] = sum_k relu(rs[n]*u[k]+v[n,k]) * W1T[k,j] ----
    for (int k0 = 0; k0 < 256; k0 += KT) {
        __syncthreads();                              // x1t reuse fence (also covers initial staging)
        for (int i = tid; i < KT * 100; i += 256) {
            int k = i & (KT - 1);
            int n = i >> 4;                           // KT == 16
            float val = rs_lds[n] * u_lds[k0 + k] + v[n * 256 + k0 + k];
            x1t[k * PAD + n] = fmaxf(val, 0.f);
        }
        float wv[KT];
#pragma unroll
        for (int k = 0; k < KT; ++k) wv[k] = W1T[(k0 + k) * 256 + j];   // coalesced
        __syncthreads();
#pragma unroll
        for (int k = 0; k < KT; ++k) {
            const float4* xr = (const float4*)&x1t[k * PAD];
#pragma unroll
            for (int p = 0; p < 25; ++p) {
                float4 xv = xr[p];                    // broadcast across lanes
                z[4 * p + 0] = fmaf(xv.x, wv[k], z[4 * p + 0]);
                z[4 * p + 1] = fmaf(xv.y, wv[k], z[4 * p + 1]);
                z[4 * p + 2] = fmaf(xv.z, wv[k], z[4 * p + 2]);
                z[4 * p + 3] = fmaf(xv.w, wv[k], z[4 * p + 3]);
            }
        }
    }

    // ---- phase 2: s_b[m] = sum_j relu( (A@Z1)[m,j] ) * w2[j] ----
    for (int m = 0; m < 100; ++m) {
        const float4* ar = (const float4*)&A_lds[m * PAD];
        float a0 = 0.f, a1 = 0.f, a2 = 0.f, a3 = 0.f;   // 4 chains for ILP
#pragma unroll
        for (int p = 0; p < 25; ++p) {
            float4 av = ar[p];
            a0 = fmaf(av.x, z[4 * p + 0], a0);
            a1 = fmaf(av.y, z[4 * p + 1], a1);
            a2 = fmaf(av.z, z[4 * p + 2], a2);
            a3 = fmaf(av.w, z[4 * p + 3], a3);
        }
        float tj = fmaxf((a0 + a1) + (a2 + a3), 0.f) * w2j;
#pragma unroll
        for (int off = 32; off; off >>= 1) tj += __shfl_xor(tj, off);
        if (lane == 0) spart[wave * 100 + m] = tj;
    }
    __syncthreads();
    if (tid < 100)
        s_lds[tid] = spart[tid] + spart[100 + tid] + spart[200 + tid] + spart[300 + tid];
    __syncthreads();

    // ---- phase 3: x3[b,n] = relu( sum_m A[n,m] * s_b[m] ) ----
    if (tid < 100) {
        const float4* ar = (const float4*)&A_lds[tid * PAD];
        float a0 = 0.f, a1 = 0.f, a2 = 0.f, a3 = 0.f;
#pragma unroll
        for (int p = 0; p < 25; ++p) {
            float4 av = ar[p];
            float4 sv = *(const float4*)&s_lds[4 * p];
            a0 = fmaf(av.x, sv.x, a0);
            a1 = fmaf(av.y, sv.y, a1);
            a2 = fmaf(av.z, sv.z, a2);
            a3 = fmaf(av.w, sv.w, a3);
        }
        x3[(long)b * 100 + tid] = fmaxf((a0 + a1) + (a2 + a3), 0.f);
    }
}

// ---------------- small glue kernels ----------------
__global__ void k_aw_rowsum(const float* __restrict__ A, const float* __restrict__ word,
                            float* __restrict__ Aw, float* __restrict__ rowsum)
{
    int i = blockIdx.x * 256 + threadIdx.x;
    if (i < 6400) {
        int n = i / 64, k = i % 64;
        float s = 0.f;
        for (int m = 0; m < 100; ++m) s += A[n * 100 + m] * word[m * 64 + k];
        Aw[i] = s;
    } else if (i < 6500) {
        int n = i - 6400;
        float s = 0.f;
        for (int m = 0; m < 100; ++m) s += A[n * 100 + m];
        rowsum[n] = s;
    }
}

// W1T[k*256+j] = W1[j*256+k]
__global__ void k_w1t(const float* __restrict__ W1, float* __restrict__ W1T)
{
    int i = blockIdx.x * 256 + threadIdx.x;    // < 65536
    int kk = i >> 8, jj = i & 255;
    W1T[i] = W1[jj * 256 + kk];
}

// fused concat [512,1098]: feats | glove_e | act_e | gcn_e
__global__ void k_fused(const float* __restrict__ feats, const float* __restrict__ ge,
                        const float* __restrict__ ae, const float* __restrict__ gcn,
                        float* __restrict__ fused)
{
    int i = blockIdx.x * 256 + threadIdx.x;       // < 512*1098
    int b = i / FUSED_IN, c = i - b * FUSED_IN;
    float v;
    if (c < 512) v = feats[(long)b * 512 + c];
    else if (c < 576) v = ge[(long)b * 64 + (c - 512)];
    else if (c < 586) v = ae[(long)b * 10 + (c - 576)];
    else v = gcn[(long)b * 512 + (c - 586)];
    fused[i] = v;
}

__global__ void k_bsum(const float* __restrict__ bih, const float* __restrict__ bhh,
                       float* __restrict__ bsum)
{
    int i = blockIdx.x * 256 + threadIdx.x;
    if (i < 2048) bsum[i] = bih[i] + bhh[i];
}

// WhhT2[h*2048 + jh*4 + g] = Whh[(g*512+jh)*512 + h]
__global__ void k_whht2(const float* __restrict__ Whh, float* __restrict__ WhhT2)
{
    int i = blockIdx.x * 256 + threadIdx.x;       // < 1048576
    int hh = i >> 11;
    int rem = i & 2047;
    int jh = rem >> 2, g = rem & 3;
    WhhT2[i] = Whh[(long)(g * 512 + jh) * 512 + hh];
}

__global__ void k_zero(float* __restrict__ p, int n)
{
    int i = blockIdx.x * 256 + threadIdx.x;
    if (i < n) p[i] = 0.f;
}

__device__ __forceinline__ float sigf(float x) { return 1.f / (1.f + __expf(-x)); }

// One LSTM time step. 32 blocks x 256 threads; thread -> (b = tid/16, jh = bx*16 + tid%16).
__global__ __launch_bounds__(256)
void lstm_step(const float* __restrict__ xWih,    // [512,2048] incl. biases
               const float* __restrict__ WhhT2,   // [512][2048] gate-interleaved
               const float* __restrict__ hPrev, const float* __restrict__ cPrev,
               float* __restrict__ hNext, float* __restrict__ cNext,
               float* __restrict__ sf, int t)
{
    __shared__ float hlds[BSZ * Hh];               // 32 KB
    const int tid = threadIdx.x;
    for (int i = tid; i < BSZ * Hh; i += 256) hlds[i] = hPrev[i];
    __syncthreads();
    const int jh = blockIdx.x * 16 + (tid & 15);
    const int b = tid >> 4;
    float ai = 0.f, af = 0.f, ag = 0.f, ao = 0.f;
    const float* hb = &hlds[b * Hh];
    const float4* wbase = (const float4*)WhhT2;
#pragma unroll 4
    for (int hh = 0; hh < Hh; ++hh) {
        float4 w = wbase[(long)hh * 512 + jh];
        float hp = hb[hh];
        ai = fmaf(w.x, hp, ai);
        af = fmaf(w.y, hp, af);
        ag = fmaf(w.z, hp, ag);
        ao = fmaf(w.w, hp, ao);
    }
    const float* xw = xWih + (long)(b * T + t) * 2048;
    float gi = xw[jh] + ai;
    float gf = xw[512 + jh] + af;
    float gg = xw[1024 + jh] + ag;
    float go = xw[1536 + jh] + ao;
    float cp = cPrev[b * Hh + jh];
    float cn = sigf(gf) * cp + sigf(gi) * tanhf(gg);
    float hn = sigf(go) * tanhf(cn);
    cNext[b * Hh + jh] = cn;
    hNext[b * Hh + jh] = hn;
    sf[(long)(b * T + t) * Hh + jh] = hn;
}

// copy final h,c into output
__global__ void k_copy_hc(const float* __restrict__ h, const float* __restrict__ c,
                          float* __restrict__ out)
{
    int i = blockIdx.x * 256 + threadIdx.x;        // < 8192
    out[3584 + i] = h[i];
    out[11776 + i] = c[i];
}

// ---------------- host ----------------
static inline void gemm(hipStream_t st, const float* A, int lda, long abs_,
                        const float* Bp, int ldb, long bbs, float* C, int ldc, long cbs,
                        const float* bias, int M, int N, int K, int batch, bool relu)
{
    dim3 g((N + BN - 1) / BN, (M + BM - 1) / BM, batch), blk(256);
    if (relu)
        hipLaunchKernelGGL((gemm_nt<true>), g, blk, 0, st, A, lda, abs_, Bp, ldb, bbs, C, ldc, cbs, bias, M, N, K);
    else
        hipLaunchKernelGGL((gemm_nt<false>), g, blk, 0, st, A, lda, abs_, Bp, ldb, bbs, C, ldc, cbs, bias, M, N, K);
}

extern "C" void kernel_launch(void* const* d_in, const int* in_sizes, int n_in,
                              void* d_out, int out_size, void* d_ws, size_t ws_size,
                              hipStream_t stream)
{
    const float* target = (const float*)d_in[0];
    const float* input_ = (const float*)d_in[1];
    const float* aprob  = (const float*)d_in[2];
    const float* Adj    = (const float*)d_in[3];
    const float* aglove = (const float*)d_in[4];
    const float* Wword  = (const float*)d_in[5];
    const float* bword  = (const float*)d_in[6];
    const float* Wg     = (const float*)d_in[7];
    const float* bg     = (const float*)d_in[8];
    const float* Wa     = (const float*)d_in[9];
    const float* ba     = (const float*)d_in[10];
    const float* W0     = (const float*)d_in[11];
    const float* W1     = (const float*)d_in[12];
    const float* W2     = (const float*)d_in[13];
    const float* Wfm    = (const float*)d_in[14];
    const float* bfm    = (const float*)d_in[15];
    const float* Wf     = (const float*)d_in[16];
    const float* bf     = (const float*)d_in[17];
    const float* Wih    = (const float*)d_in[18];
    const float* Whh    = (const float*)d_in[19];
    const float* bih    = (const float*)d_in[20];
    const float* bhh    = (const float*)d_in[21];
    const float* Wa1    = (const float*)d_in[22];
    const float* ba1    = (const float*)d_in[23];
    const float* Wa2    = (const float*)d_in[24];
    const float* ba2    = (const float*)d_in[25];
    const float* Wc1    = (const float*)d_in[26];
    const float* bc1    = (const float*)d_in[27];
    const float* Wc2    = (const float*)d_in[28];
    const float* bc2    = (const float*)d_in[29];

    float* ws = (float*)d_ws;
    float* out = (float*)d_out;

    size_t off = 0;
    auto alloc = [&](size_t n) { size_t r = off; off += (n + 255) & ~(size_t)255; return r; };
    float* glove_e = ws + alloc(512 * 64);
    float* act_e   = ws + alloc(512 * 10);
    float* u       = ws + alloc(512 * 256);
    float* word    = ws + alloc(100 * 64);
    float* Aw      = ws + alloc(100 * 64);
    float* rowsum  = ws + alloc(128);
    float* v       = ws + alloc(100 * 256);
    float* W1T     = ws + alloc(256 * 256);
    float* x3      = ws + alloc(512 * 100);
    float* gcn_e   = ws + alloc(512 * 512);
    float* fused   = ws + alloc(512 * FUSED_IN);
    float* outf    = ws + alloc(512 * 512);
    float* bsum    = ws + alloc(2048);
    float* xWih    = ws + alloc((size_t)512 * 2048);
    float* WhhT2   = ws + alloc((size_t)512 * 2048);
    float* hA      = ws + alloc(BSZ * Hh);
    float* cA      = ws + alloc(BSZ * Hh);
    float* hB      = ws + alloc(BSZ * Hh);
    float* cB      = ws + alloc(BSZ * Hh);
    float* sf      = ws + alloc(512 * 512);
    float* ah      = ws + alloc(512 * 128);
    float* ch      = ws + alloc(512 * 128);
    (void)ws_size; (void)in_sizes; (void)n_in; (void)out_size;

    const float* feats = input_; // [512,512] (trailing 1x1 squeezed)

    // --- embeddings & separable precomputes ---
    gemm(stream, target, GLOVE, 0, Wg, GLOVE, 0, glove_e, 64, 0, bg, 512, 64, GLOVE, 1, true);
    gemm(stream, aprob, ASPACE, 0, Wa, ASPACE, 0, act_e, 10, 0, ba, 512, 10, ASPACE, 1, true);
    gemm(stream, feats, 512, 0, W0, 576, 0, u, 256, 0, nullptr, 512, 256, 512, 1, false);
    gemm(stream, aglove, GLOVE, 0, Wword, GLOVE, 0, word, 64, 0, bword, 100, 64, GLOVE, 1, false);
    hipLaunchKernelGGL(k_aw_rowsum, dim3(26), dim3(256), 0, stream, Adj, word, Aw, rowsum);
    gemm(stream, Aw, 64, 0, W0 + 512, 576, 0, v, 256, 0, nullptr, 100, 256, 64, 1, false);
    hipLaunchKernelGGL(k_w1t, dim3(256), dim3(256), 0, stream, W1, W1T);

    // --- fused GCN middle: x1 -> Z1 -> X2 -> s -> x3, all in one kernel ---
    hipLaunchKernelGGL(gcn_fused, dim3(Bt), dim3(256), 0, stream, u, v, rowsum, Adj, W1T, W2, x3);

    // gcn_e = x3 @ Wfm^T + bfm : [512,512]
    gemm(stream, x3, 100, 0, Wfm, 100, 0, gcn_e, 512, 0, bfm, 512, 512, 100, 1, false);

    // --- fuse + trunk ---
    hipLaunchKernelGGL(k_fused, dim3(512 * FUSED_IN / 256), dim3(256), 0, stream, feats, glove_e, act_e, gcn_e, fused);
    gemm(stream, fused, FUSED_IN, 0, Wf, FUSED_IN, 0, outf, 512, 0, bf, 512, 512, FUSED_IN, 1, true);

    // --- LSTM precompute ---
    hipLaunchKernelGGL(k_bsum, dim3(8), dim3(256), 0, stream, bih, bhh, bsum);
    gemm(stream, outf, 512, 0, Wih, 512, 0, xWih, 2048, 0, bsum, 512, 2048, 512, 1, false);
    hipLaunchKernelGGL(k_whht2, dim3(4096), dim3(256), 0, stream, Whh, WhhT2);
    hipLaunchKernelGGL(k_zero, dim3((4 * BSZ * Hh + 255) / 256), dim3(256), 0, stream, hA, 4 * BSZ * Hh);

    // --- LSTM recurrence: 32 steps, ping-pong h/c buffers ---
    for (int t = 0; t < T; ++t) {
        const float* hp = (t & 1) ? hB : hA;
        const float* cp = (t & 1) ? cB : cA;
        float* hn = (t & 1) ? hA : hB;
        float* cn = (t & 1) ? cA : cB;
        hipLaunchKernelGGL(lstm_step, dim3(32), dim3(256), 0, stream, xWih, WhhT2, hp, cp, hn, cn, sf, t);
    }
    // after t=31 (odd), final state is in hA/cA

    // --- heads ---
    gemm(stream, sf, 512, 0, Wa1, 512, 0, ah, 128, 0, ba1, 512, 128, 512, 1, true);
    gemm(stream, ah, 128, 0, Wa2, 128, 0, out, 6, 0, ba2, 512, 6, 128, 1, true);
    gemm(stream, sf, 512, 0, Wc1, 512, 0, ch, 128, 0, bc1, 512, 128, 512, 1, true);
    gemm(stream, ch, 128, 0, Wc2, 128, 0, out + 3072, 1, 0, bc2, 512, 1, 128, 1, true);
    hipLaunchKernelGGL(k_copy_hc, dim3(32), dim3(256), 0, stream, hA, cA, out);
}

// Round 4
// 924.208 us; speedup vs baseline: 1.9458x; 1.6304x over previous
//
#include <hip/hip_runtime.h>
#include <cmath>

// ---------------- problem constants ----------------
constexpr int BSZ = 16, T = 32, NOBJ = 100;
constexpr int GLOVE = 300, GEMB = 64, ADIM = 10, GCN_DIM = 512, Hh = 512, ASPACE = 6, RES = 512;
constexpr int Bt = BSZ * T;          // 512
constexpr int FUSED_IN = RES + GEMB + ADIM + GCN_DIM; // 1098
constexpr int FP = 1120;             // padded fused width (multiple of 32, 16B-aligned rows)

// ---------------- gemm32: C = A @ B^T (+bias)(relu), fp32, high-parallelism ----------------
// BM=32, BN=64, BK=32, 128 threads, 4x4 micro-tile.
// Requirements (guaranteed by call sites): lda%4==0, ldb%4==0, ldc%4==0, K%4==0, N%4==0.
// M and K edges handled; N must be covered by grid (guarded quad-granular).
template<bool RELU>
__global__ __launch_bounds__(128)
void gemm32(const float* __restrict__ A, int lda,
            const float* __restrict__ B, int ldb,
            float* __restrict__ C, int ldc,
            const float* __restrict__ bias, int M, int N, int K)
{
    __shared__ float As[32][36];   // [k][m]
    __shared__ float Bs[32][68];   // [k][n]
    const int tid = threadIdx.x;
    const int m0 = blockIdx.y * 32, n0 = blockIdx.x * 64;
    const int mi = tid >> 4, ni = tid & 15;
    float acc[4][4] = {};
    for (int k0 = 0; k0 < K; k0 += 32) {
        __syncthreads();
#pragma unroll
        for (int l = 0; l < 2; ++l) {                 // stage A tile 32x32
            int e = tid + l * 128;
            int row = e >> 3, kq = (e & 7) << 2;
            float4 va = make_float4(0.f, 0.f, 0.f, 0.f);
            if (m0 + row < M && k0 + kq < K)
                va = *(const float4*)&A[(long)(m0 + row) * lda + k0 + kq];
            As[kq + 0][row] = va.x;
            As[kq + 1][row] = va.y;
            As[kq + 2][row] = va.z;
            As[kq + 3][row] = va.w;
        }
#pragma unroll
        for (int l = 0; l < 4; ++l) {                 // stage B tile 64x32
            int e = tid + l * 128;
            int row = e >> 3, kq = (e & 7) << 2;
            float4 vb = make_float4(0.f, 0.f, 0.f, 0.f);
            if (n0 + row < N && k0 + kq < K)
                vb = *(const float4*)&B[(long)(n0 + row) * ldb + k0 + kq];
            Bs[kq + 0][row] = vb.x;
            Bs[kq + 1][row] = vb.y;
            Bs[kq + 2][row] = vb.z;
            Bs[kq + 3][row] = vb.w;
        }
        __syncthreads();
#pragma unroll
        for (int k = 0; k < 32; ++k) {
            float4 a4 = *(const float4*)&As[k][4 * mi];
            float4 b4 = *(const float4*)&Bs[k][4 * ni];
            acc[0][0] = fmaf(a4.x, b4.x, acc[0][0]);
            acc[0][1] = fmaf(a4.x, b4.y, acc[0][1]);
            acc[0][2] = fmaf(a4.x, b4.z, acc[0][2]);
            acc[0][3] = fmaf(a4.x, b4.w, acc[0][3]);
            acc[1][0] = fmaf(a4.y, b4.x, acc[1][0]);
            acc[1][1] = fmaf(a4.y, b4.y, acc[1][1]);
            acc[1][2] = fmaf(a4.y, b4.z, acc[1][2]);
            acc[1][3] = fmaf(a4.y, b4.w, acc[1][3]);
            acc[2][0] = fmaf(a4.z, b4.x, acc[2][0]);
            acc[2][1] = fmaf(a4.z, b4.y, acc[2][1]);
            acc[2][2] = fmaf(a4.z, b4.z, acc[2][2]);
            acc[2][3] = fmaf(a4.z, b4.w, acc[2][3]);
            acc[3][0] = fmaf(a4.w, b4.x, acc[3][0]);
            acc[3][1] = fmaf(a4.w, b4.y, acc[3][1]);
            acc[3][2] = fmaf(a4.w, b4.z, acc[3][2]);
            acc[3][3] = fmaf(a4.w, b4.w, acc[3][3]);
        }
    }
    const int n = n0 + 4 * ni;
    if (n >= N) return;
    float4 bv = make_float4(0.f, 0.f, 0.f, 0.f);
    if (bias) bv = *(const float4*)&bias[n];
#pragma unroll
    for (int r = 0; r < 4; ++r) {
        int m = m0 + 4 * mi + r;
        if (m >= M) continue;
        float4 v;
        v.x = acc[r][0] + bv.x; v.y = acc[r][1] + bv.y;
        v.z = acc[r][2] + bv.z; v.w = acc[r][3] + bv.w;
        if (RELU) {
            v.x = fmaxf(v.x, 0.f); v.y = fmaxf(v.y, 0.f);
            v.z = fmaxf(v.z, 0.f); v.w = fmaxf(v.w, 0.f);
        }
        *(float4*)&C[(long)m * ldc + n] = v;
    }
}

// ---------------- old scalar GEMM (tiny / ragged cases: act_e, Wa2, Wc2) ----------------
constexpr int BM = 64, BN = 64, BK = 16;

template<bool RELU>
__global__ __launch_bounds__(256)
void gemm_nt(const float* __restrict__ A, int lda,
             const float* __restrict__ Bp, int ldb,
             float* __restrict__ C, int ldc,
             const float* __restrict__ bias, int M, int N, int K)
{
    const int m0 = blockIdx.y * BM, n0 = blockIdx.x * BN;
    __shared__ float As[BK][BM + 1];
    __shared__ float Bs[BK][BN + 1];
    const int tid = threadIdx.x;
    const int lo = tid * 4;
    const int lm = lo >> 4;
    const int lk = lo & 15;
    const int row = (tid >> 4) * 4, col = (tid & 15) * 4;
    float acc[4][4] = {};
    for (int k0 = 0; k0 < K; k0 += BK) {
#pragma unroll
        for (int e = 0; e < 4; ++e) {
            int k = lk + e;
            float va = 0.f, vb = 0.f;
            if (k0 + k < K) {
                if (m0 + lm < M) va = A[(long)(m0 + lm) * lda + k0 + k];
                if (n0 + lm < N) vb = Bp[(long)(n0 + lm) * ldb + k0 + k];
            }
            As[k][lm] = va;
            Bs[k][lm] = vb;
        }
        __syncthreads();
#pragma unroll
        for (int k = 0; k < BK; ++k) {
            float a0 = As[k][row], a1 = As[k][row + 1], a2 = As[k][row + 2], a3 = As[k][row + 3];
            float b0 = Bs[k][col], b1 = Bs[k][col + 1], b2 = Bs[k][col + 2], b3 = Bs[k][col + 3];
            acc[0][0] += a0 * b0; acc[0][1] += a0 * b1; acc[0][2] += a0 * b2; acc[0][3] += a0 * b3;
            acc[1][0] += a1 * b0; acc[1][1] += a1 * b1; acc[1][2] += a1 * b2; acc[1][3] += a1 * b3;
            acc[2][0] += a2 * b0; acc[2][1] += a2 * b1; acc[2][2] += a2 * b2; acc[2][3] += a2 * b3;
            acc[3][0] += a3 * b0; acc[3][1] += a3 * b1; acc[3][2] += a3 * b2; acc[3][3] += a3 * b3;
        }
        __syncthreads();
    }
#pragma unroll
    for (int i = 0; i < 4; ++i) {
        int m = m0 + row + i;
        if (m >= M) continue;
#pragma unroll
        for (int j = 0; j < 4; ++j) {
            int n = n0 + col + j;
            if (n >= N) continue;
            float v = acc[i][j];
            if (bias) v += bias[n];
            if (RELU) v = fmaxf(v, 0.f);
            C[(long)m * ldc + n] = v;
        }
    }
}

// ---------------- fused GCN middle (one block per b) ----------------
constexpr int KT = 16;
constexpr int PAD = 104;

__global__ __launch_bounds__(256, 3)
void gcn_fused(const float* __restrict__ u,      // [512,256]
               const float* __restrict__ v,      // [100,256]
               const float* __restrict__ rowsum, // [100]
               const float* __restrict__ A,      // [100,100]
               const float* __restrict__ W1,     // [256,256] row-major (out j, in k)
               const float* __restrict__ w2,     // [256]
               float* __restrict__ x3)           // [512,100]
{
    __shared__ float A_lds[100 * PAD];
    __shared__ float x1t[KT * PAD];
    __shared__ float u_lds[256];
    __shared__ float rs_lds[100];
    __shared__ float spart[4 * 100];
    __shared__ float s_lds[100];

    const int b = blockIdx.x;
    const int tid = threadIdx.x;
    const int lane = tid & 63, wave = tid >> 6;
    const int j = tid;

    for (int r = wave; r < 100; r += 4)
        for (int c = lane; c < 100; c += 64)
            A_lds[r * PAD + c] = A[r * 100 + c];
    u_lds[tid] = u[(long)b * 256 + tid];
    if (tid < 100) rs_lds[tid] = rowsum[tid];
    const float w2j = w2[j];
    const float4* w1p = (const float4*)(W1 + (long)j * 256);  // own row of W1

    float z[100];
#pragma unroll
    for (int n = 0; n < 100; ++n) z[n] = 0.f;

    // phase 1: z[n] = sum_k relu(rs[n]*u[k]+v[n,k]) * W1[j,k]
    for (int k0 = 0; k0 < 256; k0 += KT) {
        __syncthreads();
        for (int i = tid; i < KT * 100; i += 256) {
            int k = i & (KT - 1);
            int n = i >> 4;
            float val = rs_lds[n] * u_lds[k0 + k] + v[n * 256 + k0 + k];
            x1t[k * PAD + n] = fmaxf(val, 0.f);
        }
        float4 wq0 = w1p[(k0 >> 2) + 0];
        float4 wq1 = w1p[(k0 >> 2) + 1];
        float4 wq2 = w1p[(k0 >> 2) + 2];
        float4 wq3 = w1p[(k0 >> 2) + 3];
        float wv[KT] = {wq0.x, wq0.y, wq0.z, wq0.w, wq1.x, wq1.y, wq1.z, wq1.w,
                        wq2.x, wq2.y, wq2.z, wq2.w, wq3.x, wq3.y, wq3.z, wq3.w};
        __syncthreads();
#pragma unroll
        for (int k = 0; k < KT; ++k) {
            const float4* xr = (const float4*)&x1t[k * PAD];
#pragma unroll
            for (int p = 0; p < 25; ++p) {
                float4 xv = xr[p];
                z[4 * p + 0] = fmaf(xv.x, wv[k], z[4 * p + 0]);
                z[4 * p + 1] = fmaf(xv.y, wv[k], z[4 * p + 1]);
                z[4 * p + 2] = fmaf(xv.z, wv[k], z[4 * p + 2]);
                z[4 * p + 3] = fmaf(xv.w, wv[k], z[4 * p + 3]);
            }
        }
    }

    // phase 2: s[m] = sum_j relu((A@Z1)[m,j]) * w2[j]
    for (int m = 0; m < 100; ++m) {
        const float4* ar = (const float4*)&A_lds[m * PAD];
        float a0 = 0.f, a1 = 0.f, a2 = 0.f, a3 = 0.f;
#pragma unroll
        for (int p = 0; p < 25; ++p) {
            float4 av = ar[p];
            a0 = fmaf(av.x, z[4 * p + 0], a0);
            a1 = fmaf(av.y, z[4 * p + 1], a1);
            a2 = fmaf(av.z, z[4 * p + 2], a2);
            a3 = fmaf(av.w, z[4 * p + 3], a3);
        }
        float tj = fmaxf((a0 + a1) + (a2 + a3), 0.f) * w2j;
#pragma unroll
        for (int off = 32; off; off >>= 1) tj += __shfl_xor(tj, off);
        if (lane == 0) spart[wave * 100 + m] = tj;
    }
    __syncthreads();
    if (tid < 100)
        s_lds[tid] = spart[tid] + spart[100 + tid] + spart[200 + tid] + spart[300 + tid];
    __syncthreads();

    // phase 3: x3[b,n] = relu(sum_m A[n,m] * s[m])
    if (tid < 100) {
        const float4* ar = (const float4*)&A_lds[tid * PAD];
        float a0 = 0.f, a1 = 0.f, a2 = 0.f, a3 = 0.f;
#pragma unroll
        for (int p = 0; p < 25; ++p) {
            float4 av = ar[p];
            float4 sv = *(const float4*)&s_lds[4 * p];
            a0 = fmaf(av.x, sv.x, a0);
            a1 = fmaf(av.y, sv.y, a1);
            a2 = fmaf(av.z, sv.z, a2);
            a3 = fmaf(av.w, sv.w, a3);
        }
        x3[(long)b * 100 + tid] = fmaxf((a0 + a1) + (a2 + a3), 0.f);
    }
}

// ---------------- glue kernels ----------------
__global__ void k_aw_rowsum(const float* __restrict__ A, const float* __restrict__ word,
                            float* __restrict__ Aw, float* __restrict__ rowsum)
{
    int i = blockIdx.x * 256 + threadIdx.x;
    if (i < 6400) {
        int n = i / 64, k = i % 64;
        float s = 0.f;
        for (int m = 0; m < 100; ++m) s += A[n * 100 + m] * word[m * 64 + k];
        Aw[i] = s;
    } else if (i < 6500) {
        int n = i - 6400;
        float s = 0.f;
        for (int m = 0; m < 100; ++m) s += A[n * 100 + m];
        rowsum[n] = s;
    }
}

// merged preprocessing: WhhT2 transpose | Wf pad-copy | zero h/c | bias sum
__global__ void k_prep(const float* __restrict__ Whh, float* __restrict__ WhhT2,
                       const float* __restrict__ Wf, float* __restrict__ WfP,
                       float* __restrict__ hzero,
                       const float* __restrict__ bih, const float* __restrict__ bhh,
                       float* __restrict__ bsum)
{
    int bx = blockIdx.x, tid = threadIdx.x;
    if (bx < 4096) {
        int i = bx * 256 + tid;                     // < 1048576
        int hh = i >> 11, rem = i & 2047, jh = rem >> 2, g = rem & 3;
        WhhT2[i] = Whh[(long)(g * 512 + jh) * 512 + hh];
    } else if (bx < 4096 + 2240) {
        int i = (bx - 4096) * 256 + tid;            // < 512*1120
        int r = i / FP, c = i - r * FP;
        WfP[i] = (c < FUSED_IN) ? Wf[(long)r * FUSED_IN + c] : 0.f;
    } else if (bx < 4096 + 2240 + 128) {
        int i = (bx - 6336) * 256 + tid;            // < 32768
        hzero[i] = 0.f;
    } else {
        int i = (bx - 6464) * 256 + tid;            // < 2048
        bsum[i] = bih[i] + bhh[i];
    }
}

// fused concat, padded to FP: feats | glove_e | act_e | gcn_e | zeros
__global__ void k_fused(const float* __restrict__ feats, const float* __restrict__ ge,
                        const float* __restrict__ ae, const float* __restrict__ gcn,
                        float* __restrict__ fused)
{
    int i = blockIdx.x * 256 + threadIdx.x;       // < 512*1120
    int b = i / FP, c = i - b * FP;
    float v = 0.f;
    if (c < 512) v = feats[(long)b * 512 + c];
    else if (c < 576) v = ge[(long)b * 64 + (c - 512)];
    else if (c < 586) v = ae[(long)b * 10 + (c - 576)];
    else if (c < 1098) v = gcn[(long)b * 512 + (c - 586)];
    fused[i] = v;
}

__device__ __forceinline__ float sigf(float x) { return 1.f / (1.f + __expf(-x)); }

// LSTM step v2: 256 blocks x 256 threads; block covers 2 jh columns, 8-way K-split.
__global__ __launch_bounds__(256)
void lstm_step2(const float* __restrict__ xWih,   // [512,2048] rows b*T+t
                const float4* __restrict__ W4,    // WhhT2 as float4 [hh][jh]
                const float* __restrict__ hPrev, const float* __restrict__ cPrev,
                float* __restrict__ hNext, float* __restrict__ cNext,
                float* __restrict__ sf, int t)
{
    __shared__ float hlds[512 * 17];              // [hh][b], padded stride 17
    __shared__ float4 pex[256];
    const int tid = threadIdx.x;
    const float4* hp4 = (const float4*)hPrev;
#pragma unroll
    for (int l = 0; l < 8; ++l) {
        int i4 = tid + l * 256;                   // 0..2047
        int bb = i4 >> 7, hq = i4 & 127;
        float4 h4 = hp4[i4];
        int hh0 = hq * 4;
        hlds[(hh0 + 0) * 17 + bb] = h4.x;
        hlds[(hh0 + 1) * 17 + bb] = h4.y;
        hlds[(hh0 + 2) * 17 + bb] = h4.z;
        hlds[(hh0 + 3) * 17 + bb] = h4.w;
    }
    __syncthreads();
    const int b = tid & 15, j2 = (tid >> 4) & 1, ks = tid >> 5;
    const int jh = blockIdx.x * 2 + j2;
    float ai = 0.f, af = 0.f, ag = 0.f, ao = 0.f;
    const float4* wcol = W4 + jh;
    int hh = ks * 64;
#pragma unroll 4
    for (int r = 0; r < 64; ++r, ++hh) {
        float4 w = wcol[(long)hh * 512];
        float hp = hlds[hh * 17 + b];
        ai = fmaf(w.x, hp, ai);
        af = fmaf(w.y, hp, af);
        ag = fmaf(w.z, hp, ag);
        ao = fmaf(w.w, hp, ao);
    }
    pex[tid] = make_float4(ai, af, ag, ao);
    __syncthreads();
    if (tid < 32) {
        int fb = tid & 15, fj = tid >> 4;
        float gi = 0.f, gf = 0.f, gg = 0.f, go = 0.f;
#pragma unroll
        for (int k = 0; k < 8; ++k) {
            float4 p = pex[k * 32 + fj * 16 + fb];
            gi += p.x; gf += p.y; gg += p.z; go += p.w;
        }
        int jhf = blockIdx.x * 2 + fj;
        const float* xw = xWih + (long)(fb * T + t) * 2048;
        gi += xw[jhf]; gf += xw[512 + jhf]; gg += xw[1024 + jhf]; go += xw[1536 + jhf];
        float cp = cPrev[fb * 512 + jhf];
        float cn = sigf(gf) * cp + sigf(gi) * tanhf(gg);
        float hn = sigf(go) * tanhf(cn);
        cNext[fb * 512 + jhf] = cn;
        hNext[fb * 512 + jhf] = hn;
        sf[(long)(fb * T + t) * 512 + jhf] = hn;
    }
}

__global__ void k_copy_hc(const float* __restrict__ h, const float* __restrict__ c,
                          float* __restrict__ out)
{
    int i = blockIdx.x * 256 + threadIdx.x;        // < 8192
    out[3584 + i] = h[i];
    out[11776 + i] = c[i];
}

// ---------------- host ----------------
static inline void g32(hipStream_t st, const float* A, int lda, const float* B, int ldb,
                       float* C, int ldc, const float* bias, int M, int N, int K, bool relu)
{
    dim3 g((N + 63) / 64, (M + 31) / 32), blk(128);
    if (relu) hipLaunchKernelGGL((gemm32<true>), g, blk, 0, st, A, lda, B, ldb, C, ldc, bias, M, N, K);
    else      hipLaunchKernelGGL((gemm32<false>), g, blk, 0, st, A, lda, B, ldb, C, ldc, bias, M, N, K);
}
static inline void gnt(hipStream_t st, const float* A, int lda, const float* B, int ldb,
                       float* C, int ldc, const float* bias, int M, int N, int K, bool relu)
{
    dim3 g((N + BN - 1) / BN, (M + BM - 1) / BM), blk(256);
    if (relu) hipLaunchKernelGGL((gemm_nt<true>), g, blk, 0, st, A, lda, B, ldb, C, ldc, bias, M, N, K);
    else      hipLaunchKernelGGL((gemm_nt<false>), g, blk, 0, st, A, lda, B, ldb, C, ldc, bias, M, N, K);
}

extern "C" void kernel_launch(void* const* d_in, const int* in_sizes, int n_in,
                              void* d_out, int out_size, void* d_ws, size_t ws_size,
                              hipStream_t stream)
{
    const float* target = (const float*)d_in[0];
    const float* input_ = (const float*)d_in[1];
    const float* aprob  = (const float*)d_in[2];
    const float* Adj    = (const float*)d_in[3];
    const float* aglove = (const float*)d_in[4];
    const float* Wword  = (const float*)d_in[5];
    const float* bword  = (const float*)d_in[6];
    const float* Wg     = (const float*)d_in[7];
    const float* bg     = (const float*)d_in[8];
    const float* Wa     = (const float*)d_in[9];
    const float* ba     = (const float*)d_in[10];
    const float* W0     = (const float*)d_in[11];
    const float* W1     = (const float*)d_in[12];
    const float* W2     = (const float*)d_in[13];
    const float* Wfm    = (const float*)d_in[14];
    const float* bfm    = (const float*)d_in[15];
    const float* Wf     = (const float*)d_in[16];
    const float* bf     = (const float*)d_in[17];
    const float* Wih    = (const float*)d_in[18];
    const float* Whh    = (const float*)d_in[19];
    const float* bih    = (const float*)d_in[20];
    const float* bhh    = (const float*)d_in[21];
    const float* Wa1    = (const float*)d_in[22];
    const float* ba1    = (const float*)d_in[23];
    const float* Wa2    = (const float*)d_in[24];
    const float* ba2    = (const float*)d_in[25];
    const float* Wc1    = (const float*)d_in[26];
    const float* bc1    = (const float*)d_in[27];
    const float* Wc2    = (const float*)d_in[28];
    const float* bc2    = (const float*)d_in[29];

    float* ws = (float*)d_ws;
    float* out = (float*)d_out;

    size_t off = 0;
    auto alloc = [&](size_t n) { size_t r = off; off += (n + 255) & ~(size_t)255; return r; };
    float* glove_e = ws + alloc(512 * 64);
    float* act_e   = ws + alloc(512 * 10);
    float* u       = ws + alloc(512 * 256);
    float* word    = ws + alloc(100 * 64);
    float* Aw      = ws + alloc(100 * 64);
    float* rowsum  = ws + alloc(128);
    float* v       = ws + alloc(100 * 256);
    float* x3      = ws + alloc(512 * 100);
    float* gcn_e   = ws + alloc(512 * 512);
    float* fused   = ws + alloc((size_t)512 * FP);
    float* WfP     = ws + alloc((size_t)512 * FP);
    float* outf    = ws + alloc(512 * 512);
    float* bsum    = ws + alloc(2048);
    float* xWih    = ws + alloc((size_t)512 * 2048);
    float* WhhT2   = ws + alloc((size_t)512 * 2048);
    float* hA      = ws + alloc(BSZ * Hh);
    float* cA      = ws + alloc(BSZ * Hh);
    float* hB      = ws + alloc(BSZ * Hh);
    float* cB      = ws + alloc(BSZ * Hh);
    float* sf      = ws + alloc(512 * 512);
    float* ah      = ws + alloc(512 * 128);
    float* ch      = ws + alloc(512 * 128);
    (void)ws_size; (void)in_sizes; (void)n_in; (void)out_size;

    const float* feats = input_; // [512,512]

    // --- independent preprocessing (WhhT2, WfP, zero h/c, bias sum) ---
    hipLaunchKernelGGL(k_prep, dim3(6472), dim3(256), 0, stream,
                       Whh, WhhT2, Wf, WfP, hA, bih, bhh, bsum);

    // --- embeddings & separable precomputes ---
    g32(stream, target, GLOVE, Wg, GLOVE, glove_e, 64, bg, 512, 64, GLOVE, true);
    gnt(stream, aprob, ASPACE, Wa, ASPACE, act_e, 10, ba, 512, 10, ASPACE, true);
    g32(stream, feats, 512, W0, 576, u, 256, nullptr, 512, 256, 512, false);
    g32(stream, aglove, GLOVE, Wword, GLOVE, word, 64, bword, 100, 64, GLOVE, false);
    hipLaunchKernelGGL(k_aw_rowsum, dim3(26), dim3(256), 0, stream, Adj, word, Aw, rowsum);
    g32(stream, Aw, 64, W0 + 512, 576, v, 256, nullptr, 100, 256, 64, false);

    // --- fused GCN middle ---
    hipLaunchKernelGGL(gcn_fused, dim3(Bt), dim3(256), 0, stream, u, v, rowsum, Adj, W1, W2, x3);
    g32(stream, x3, 100, Wfm, 100, gcn_e, 512, bfm, 512, 512, 100, false);

    // --- fuse + trunk ---
    hipLaunchKernelGGL(k_fused, dim3(512 * FP / 256), dim3(256), 0, stream,
                       feats, glove_e, act_e, gcn_e, fused);
    g32(stream, fused, FP, WfP, FP, outf, 512, bf, 512, 512, FP, true);
    g32(stream, outf, 512, Wih, 512, xWih, 2048, bsum, 512, 2048, 512, false);

    // --- LSTM recurrence ---
    for (int t = 0; t < T; ++t) {
        const float* hp = (t & 1) ? hB : hA;
        const float* cp = (t & 1) ? cB : cA;
        float* hn = (t & 1) ? hA : hB;
        float* cn = (t & 1) ? cA : cB;
        hipLaunchKernelGGL(lstm_step2, dim3(256), dim3(256), 0, stream,
                           xWih, (const float4*)WhhT2, hp, cp, hn, cn, sf, t);
    }
    // t=31 odd -> final state in hA/cA

    // --- heads ---
    g32(stream, sf, 512, Wa1, 512, ah, 128, ba1, 512, 128, 512, true);
    gnt(stream, ah, 128, Wa2, 128, out, 6, ba2, 512, 6, 128, true);
    g32(stream, sf, 512, Wc1, 512, ch, 128, bc1, 512, 128, 512, true);
    gnt(stream, ch, 128, Wc2, 128, out + 3072, 1, bc2, 512, 1, 128, true);
    hipLaunchKernelGGL(k_copy_hc, dim3(32), dim3(256), 0, stream, hA, cA, out);
}

// Round 5
// 660.422 us; speedup vs baseline: 2.7230x; 1.3994x over previous
//
#include <hip/hip_runtime.h>
#include <cmath>

// ---------------- problem constants ----------------
constexpr int BSZ = 16, T = 32, NOBJ = 100;
constexpr int GLOVE = 300, GEMB = 64, ADIM = 10, GCN_DIM = 512, Hh = 512, ASPACE = 6, RES = 512;
constexpr int Bt = BSZ * T;          // 512
constexpr int FUSED_IN = RES + GEMB + ADIM + GCN_DIM; // 1098
constexpr int FP = 1120;             // padded fused width

typedef __attribute__((ext_vector_type(8))) short bf16x8;
typedef __attribute__((ext_vector_type(4))) float f32x4;

__device__ __forceinline__ unsigned short f2bf(float f) {
    unsigned u = __float_as_uint(f);
    return (unsigned short)((u + 0x7FFFu + ((u >> 16) & 1u)) >> 16);
}
__device__ __forceinline__ unsigned pk2(float a, float b) {
    return (unsigned)f2bf(a) | ((unsigned)f2bf(b) << 16);
}

// ---------------- gemm32: C = A @ B^T (+bias)(relu), fp32 ----------------
template<bool RELU>
__global__ __launch_bounds__(128)
void gemm32(const float* __restrict__ A, int lda,
            const float* __restrict__ B, int ldb,
            float* __restrict__ C, int ldc,
            const float* __restrict__ bias, int M, int N, int K)
{
    __shared__ float As[32][36];
    __shared__ float Bs[32][68];
    const int tid = threadIdx.x;
    const int m0 = blockIdx.y * 32, n0 = blockIdx.x * 64;
    const int mi = tid >> 4, ni = tid & 15;
    float acc[4][4] = {};
    for (int k0 = 0; k0 < K; k0 += 32) {
        __syncthreads();
#pragma unroll
        for (int l = 0; l < 2; ++l) {
            int e = tid + l * 128;
            int row = e >> 3, kq = (e & 7) << 2;
            float4 va = make_float4(0.f, 0.f, 0.f, 0.f);
            if (m0 + row < M && k0 + kq < K)
                va = *(const float4*)&A[(long)(m0 + row) * lda + k0 + kq];
            As[kq + 0][row] = va.x; As[kq + 1][row] = va.y;
            As[kq + 2][row] = va.z; As[kq + 3][row] = va.w;
        }
#pragma unroll
        for (int l = 0; l < 4; ++l) {
            int e = tid + l * 128;
            int row = e >> 3, kq = (e & 7) << 2;
            float4 vb = make_float4(0.f, 0.f, 0.f, 0.f);
            if (n0 + row < N && k0 + kq < K)
                vb = *(const float4*)&B[(long)(n0 + row) * ldb + k0 + kq];
            Bs[kq + 0][row] = vb.x; Bs[kq + 1][row] = vb.y;
            Bs[kq + 2][row] = vb.z; Bs[kq + 3][row] = vb.w;
        }
        __syncthreads();
#pragma unroll
        for (int k = 0; k < 32; ++k) {
            float4 a4 = *(const float4*)&As[k][4 * mi];
            float4 b4 = *(const float4*)&Bs[k][4 * ni];
            acc[0][0] = fmaf(a4.x, b4.x, acc[0][0]); acc[0][1] = fmaf(a4.x, b4.y, acc[0][1]);
            acc[0][2] = fmaf(a4.x, b4.z, acc[0][2]); acc[0][3] = fmaf(a4.x, b4.w, acc[0][3]);
            acc[1][0] = fmaf(a4.y, b4.x, acc[1][0]); acc[1][1] = fmaf(a4.y, b4.y, acc[1][1]);
            acc[1][2] = fmaf(a4.y, b4.z, acc[1][2]); acc[1][3] = fmaf(a4.y, b4.w, acc[1][3]);
            acc[2][0] = fmaf(a4.z, b4.x, acc[2][0]); acc[2][1] = fmaf(a4.z, b4.y, acc[2][1]);
            acc[2][2] = fmaf(a4.z, b4.z, acc[2][2]); acc[2][3] = fmaf(a4.z, b4.w, acc[2][3]);
            acc[3][0] = fmaf(a4.w, b4.x, acc[3][0]); acc[3][1] = fmaf(a4.w, b4.y, acc[3][1]);
            acc[3][2] = fmaf(a4.w, b4.z, acc[3][2]); acc[3][3] = fmaf(a4.w, b4.w, acc[3][3]);
        }
    }
    const int n = n0 + 4 * ni;
    if (n >= N) return;
    float4 bv = make_float4(0.f, 0.f, 0.f, 0.f);
    if (bias) bv = *(const float4*)&bias[n];
#pragma unroll
    for (int r = 0; r < 4; ++r) {
        int m = m0 + 4 * mi + r;
        if (m >= M) continue;
        float4 v;
        v.x = acc[r][0] + bv.x; v.y = acc[r][1] + bv.y;
        v.z = acc[r][2] + bv.z; v.w = acc[r][3] + bv.w;
        if (RELU) {
            v.x = fmaxf(v.x, 0.f); v.y = fmaxf(v.y, 0.f);
            v.z = fmaxf(v.z, 0.f); v.w = fmaxf(v.w, 0.f);
        }
        *(float4*)&C[(long)m * ldc + n] = v;
    }
}

// ---------------- scalar GEMM for ragged tiny cases ----------------
constexpr int BM = 64, BN = 64, BK = 16;
template<bool RELU>
__global__ __launch_bounds__(256)
void gemm_nt(const float* __restrict__ A, int lda,
             const float* __restrict__ Bp, int ldb,
             float* __restrict__ C, int ldc,
             const float* __restrict__ bias, int M, int N, int K)
{
    const int m0 = blockIdx.y * BM, n0 = blockIdx.x * BN;
    __shared__ float As[BK][BM + 1];
    __shared__ float Bs[BK][BN + 1];
    const int tid = threadIdx.x;
    const int lo = tid * 4;
    const int lm = lo >> 4;
    const int lk = lo & 15;
    const int row = (tid >> 4) * 4, col = (tid & 15) * 4;
    float acc[4][4] = {};
    for (int k0 = 0; k0 < K; k0 += BK) {
#pragma unroll
        for (int e = 0; e < 4; ++e) {
            int k = lk + e;
            float va = 0.f, vb = 0.f;
            if (k0 + k < K) {
                if (m0 + lm < M) va = A[(long)(m0 + lm) * lda + k0 + k];
                if (n0 + lm < N) vb = Bp[(long)(n0 + lm) * ldb + k0 + k];
            }
            As[k][lm] = va;
            Bs[k][lm] = vb;
        }
        __syncthreads();
#pragma unroll
        for (int k = 0; k < BK; ++k) {
            float a0 = As[k][row], a1 = As[k][row + 1], a2 = As[k][row + 2], a3 = As[k][row + 3];
            float b0 = Bs[k][col], b1 = Bs[k][col + 1], b2 = Bs[k][col + 2], b3 = Bs[k][col + 3];
            acc[0][0] += a0 * b0; acc[0][1] += a0 * b1; acc[0][2] += a0 * b2; acc[0][3] += a0 * b3;
            acc[1][0] += a1 * b0; acc[1][1] += a1 * b1; acc[1][2] += a1 * b2; acc[1][3] += a1 * b3;
            acc[2][0] += a2 * b0; acc[2][1] += a2 * b1; acc[2][2] += a2 * b2; acc[2][3] += a2 * b3;
            acc[3][0] += a3 * b0; acc[3][1] += a3 * b1; acc[3][2] += a3 * b2; acc[3][3] += a3 * b3;
        }
        __syncthreads();
    }
#pragma unroll
    for (int i = 0; i < 4; ++i) {
        int m = m0 + row + i;
        if (m >= M) continue;
#pragma unroll
        for (int j = 0; j < 4; ++j) {
            int n = n0 + col + j;
            if (n >= N) continue;
            float v = acc[i][j];
            if (bias) v += bias[n];
            if (RELU) v = fmaxf(v, 0.f);
            C[(long)m * ldc + n] = v;
        }
    }
}

// ---------------- fused GCN middle, MFMA version ----------------
// One block per b. 4 waves. mfma_f32_16x16x32_bf16.
// Phase 1: Z1[112,256] = X1 @ W1^T (X1 gen'd on the fly; W1 fragment-major bf16 in global).
//   j processed in 2 halves of 128 so Z1T (bf16 [128j][136n]) fits LDS.
// Phase 2: X2 = A @ Z1 (A fragment-major bf16, zero-padded 112x128), fused relu*w2 -> s.
// Phase 3: x3 = relu(A @ s) in VALU.
// A/B frags share the same lane->k map (correct under any HW k-permutation);
// C/D map col=lane&15, row=(lane>>4)*4+reg (HW-verified m89).
__global__ __launch_bounds__(256, 2)
void gcn_fused(const float* __restrict__ u,      // [512,256]
               const float* __restrict__ v,      // [100,256]
               const float* __restrict__ rowsum, // [100]
               const float* __restrict__ Aglob,  // [100,100] fp32
               const bf16x8* __restrict__ W1f,   // [16jt][8kt][64lane] frags
               const bf16x8* __restrict__ Af,    // [7mt][4kt][64lane] frags
               const float* __restrict__ w2,     // [256]
               float* __restrict__ x3)           // [512,100]
{
    __shared__ unsigned short X1s[112 * 40];    // [n][k-tile 32 + pad 8]
    __shared__ unsigned short Z1Ts[128 * 136];  // [j_local][n + pad]
    __shared__ float u_lds[256];
    __shared__ float rs_lds[112];
    __shared__ float w2l[256];
    __shared__ float spart[4][112];
    __shared__ float sl[112];

    const int b = blockIdx.x, tid = threadIdx.x;
    const int l = tid & 63, wv = tid >> 6;
    const int lrow = l & 15, kg = l >> 4;

    u_lds[tid] = u[(long)b * 256 + tid];
    w2l[tid] = w2[tid];
    if (tid < 112) rs_lds[tid] = (tid < 100) ? rowsum[tid] : 0.f;
    if (tid < 128) {                            // zero Z1T n-pad [112,128)
        uint4 z = make_uint4(0, 0, 0, 0);
        *(uint4*)&Z1Ts[tid * 136 + 112] = z;
        *(uint4*)&Z1Ts[tid * 136 + 120] = z;
    }

    float sacc[7][4];
#pragma unroll
    for (int mt = 0; mt < 7; ++mt)
#pragma unroll
        for (int r = 0; r < 4; ++r) sacc[mt][r] = 0.f;

    for (int half = 0; half < 2; ++half) {
        f32x4 acc1[7][2];
#pragma unroll
        for (int mt = 0; mt < 7; ++mt)
#pragma unroll
            for (int jtl = 0; jtl < 2; ++jtl) acc1[mt][jtl] = (f32x4){0.f, 0.f, 0.f, 0.f};

        for (int kt = 0; kt < 8; ++kt) {
            __syncthreads();                     // X1s safe to overwrite
            if (tid < 224) {                     // generate X1 tile [112 n][32 k] bf16
                int n = tid >> 1, kh = (tid & 1) << 4;
                int kb = kt * 32 + kh;
                uint4 p0 = make_uint4(0, 0, 0, 0), p1 = make_uint4(0, 0, 0, 0);
                if (n < 100) {
                    float rsn = rs_lds[n];
                    const float4* vp = (const float4*)&v[n * 256 + kb];
                    float4 u0 = *(const float4*)&u_lds[kb];
                    float4 u1 = *(const float4*)&u_lds[kb + 4];
                    float4 u2 = *(const float4*)&u_lds[kb + 8];
                    float4 u3 = *(const float4*)&u_lds[kb + 12];
                    float4 v0 = vp[0], v1 = vp[1], v2 = vp[2], v3 = vp[3];
                    float x0 = fmaxf(fmaf(rsn, u0.x, v0.x), 0.f), x1 = fmaxf(fmaf(rsn, u0.y, v0.y), 0.f);
                    float x2 = fmaxf(fmaf(rsn, u0.z, v0.z), 0.f), x3v = fmaxf(fmaf(rsn, u0.w, v0.w), 0.f);
                    float x4 = fmaxf(fmaf(rsn, u1.x, v1.x), 0.f), x5 = fmaxf(fmaf(rsn, u1.y, v1.y), 0.f);
                    float x6 = fmaxf(fmaf(rsn, u1.z, v1.z), 0.f), x7 = fmaxf(fmaf(rsn, u1.w, v1.w), 0.f);
                    float x8 = fmaxf(fmaf(rsn, u2.x, v2.x), 0.f), x9 = fmaxf(fmaf(rsn, u2.y, v2.y), 0.f);
                    float xa = fmaxf(fmaf(rsn, u2.z, v2.z), 0.f), xb = fmaxf(fmaf(rsn, u2.w, v2.w), 0.f);
                    float xc = fmaxf(fmaf(rsn, u3.x, v3.x), 0.f), xd = fmaxf(fmaf(rsn, u3.y, v3.y), 0.f);
                    float xe = fmaxf(fmaf(rsn, u3.z, v3.z), 0.f), xf = fmaxf(fmaf(rsn, u3.w, v3.w), 0.f);
                    p0 = make_uint4(pk2(x0, x1), pk2(x2, x3v), pk2(x4, x5), pk2(x6, x7));
                    p1 = make_uint4(pk2(x8, x9), pk2(xa, xb), pk2(xc, xd), pk2(xe, xf));
                }
                *(uint4*)&X1s[n * 40 + kh] = p0;
                *(uint4*)&X1s[n * 40 + kh + 8] = p1;
            }
            __syncthreads();                     // X1s ready
            bf16x8 af[7];
#pragma unroll
            for (int mt = 0; mt < 7; ++mt)
                af[mt] = *(const bf16x8*)&X1s[(mt * 16 + lrow) * 40 + kg * 8];
#pragma unroll
            for (int jtl = 0; jtl < 2; ++jtl) {
                int jt = half * 8 + wv * 2 + jtl;
                bf16x8 bf = W1f[(jt * 8 + kt) * 64 + l];
#pragma unroll
                for (int mt = 0; mt < 7; ++mt)
                    acc1[mt][jtl] = __builtin_amdgcn_mfma_f32_16x16x32_bf16(af[mt], bf, acc1[mt][jtl], 0, 0, 0);
            }
        }

        // write Z1T (wave-private rows), bf16
#pragma unroll
        for (int mt = 0; mt < 7; ++mt)
#pragma unroll
            for (int jtl = 0; jtl < 2; ++jtl) {
                int jloc = (wv * 2 + jtl) * 16 + lrow;
                f32x4 a = acc1[mt][jtl];
                uint2 zz;
                zz.x = pk2(a[0], a[1]);
                zz.y = pk2(a[2], a[3]);
                *(uint2*)&Z1Ts[jloc * 136 + mt * 16 + kg * 4] = zz;
            }

        // phase 2 (same-wave read of just-written rows; lgkmcnt orders it)
        bf16x8 bz[2][4];
#pragma unroll
        for (int jtl = 0; jtl < 2; ++jtl)
#pragma unroll
            for (int k2 = 0; k2 < 4; ++k2)
                bz[jtl][k2] = *(const bf16x8*)&Z1Ts[((wv * 2 + jtl) * 16 + lrow) * 136 + k2 * 32 + kg * 8];
#pragma unroll
        for (int mt = 0; mt < 7; ++mt) {
            bf16x8 aA[4];
#pragma unroll
            for (int k2 = 0; k2 < 4; ++k2) aA[k2] = Af[(mt * 4 + k2) * 64 + l];
#pragma unroll
            for (int jtl = 0; jtl < 2; ++jtl) {
                f32x4 p = (f32x4){0.f, 0.f, 0.f, 0.f};
#pragma unroll
                for (int k2 = 0; k2 < 4; ++k2)
                    p = __builtin_amdgcn_mfma_f32_16x16x32_bf16(aA[k2], bz[jtl][k2], p, 0, 0, 0);
                float w2j = w2l[half * 128 + (wv * 2 + jtl) * 16 + lrow];
#pragma unroll
                for (int r = 0; r < 4; ++r)
                    sacc[mt][r] = fmaf(fmaxf(p[r], 0.f), w2j, sacc[mt][r]);
            }
        }
    }

    // reduce sacc over j (low 4 lane bits) -> spart
#pragma unroll
    for (int mt = 0; mt < 7; ++mt) {
        float s0 = sacc[mt][0], s1 = sacc[mt][1], s2 = sacc[mt][2], s3 = sacc[mt][3];
#pragma unroll
        for (int off = 1; off < 16; off <<= 1) {
            s0 += __shfl_xor(s0, off);
            s1 += __shfl_xor(s1, off);
            s2 += __shfl_xor(s2, off);
            s3 += __shfl_xor(s3, off);
        }
        if (lrow == 0) {
            int m = mt * 16 + kg * 4;
            spart[wv][m + 0] = s0; spart[wv][m + 1] = s1;
            spart[wv][m + 2] = s2; spart[wv][m + 3] = s3;
        }
    }
    __syncthreads();
    if (tid < 112)
        sl[tid] = spart[0][tid] + spart[1][tid] + spart[2][tid] + spart[3][tid];
    __syncthreads();

    // phase 3: x3[b,n] = relu(sum_m A[n,m]*s[m])
    float sv0 = (l < 100) ? sl[l] : 0.f;
    float sv1 = (l + 64 < 100) ? sl[l + 64] : 0.f;
#pragma unroll 5
    for (int i = 0; i < 25; ++i) {
        int n = i * 4 + wv;
        float a0 = (l < 100) ? Aglob[n * 100 + l] : 0.f;
        float a1 = (l + 64 < 100) ? Aglob[n * 100 + l + 64] : 0.f;
        float p = a0 * sv0 + a1 * sv1;
#pragma unroll
        for (int off = 32; off; off >>= 1) p += __shfl_xor(p, off);
        if (l == 0) x3[(long)b * 100 + n] = fmaxf(p, 0.f);
    }
}

// ---------------- glue kernels ----------------
__global__ void k_aw_rowsum(const float* __restrict__ A, const float* __restrict__ word,
                            float* __restrict__ Aw, float* __restrict__ rowsum)
{
    int i = blockIdx.x * 256 + threadIdx.x;
    if (i < 6400) {
        int n = i / 64, k = i % 64;
        float s = 0.f;
        for (int m = 0; m < 100; ++m) s += A[n * 100 + m] * word[m * 64 + k];
        Aw[i] = s;
    } else if (i < 6500) {
        int n = i - 6400;
        float s = 0.f;
        for (int m = 0; m < 100; ++m) s += A[n * 100 + m];
        rowsum[n] = s;
    }
}

// merged preprocessing: WhhT2 | WfP pad | zero h/c | bsum | W1 frags | A frags
__global__ void k_prep(const float* __restrict__ Whh, float* __restrict__ WhhT2,
                       const float* __restrict__ Wf, float* __restrict__ WfP,
                       float* __restrict__ hzero,
                       const float* __restrict__ bih, const float* __restrict__ bhh,
                       float* __restrict__ bsum,
                       const float* __restrict__ W1, uint4* __restrict__ W1f,
                       const float* __restrict__ A, uint4* __restrict__ Af)
{
    int bx = blockIdx.x, tid = threadIdx.x;
    if (bx < 4096) {
        int i = bx * 256 + tid;
        int hh = i >> 11, rem = i & 2047, jh = rem >> 2, g = rem & 3;
        WhhT2[i] = Whh[(long)(g * 512 + jh) * 512 + hh];
    } else if (bx < 6336) {
        int i = (bx - 4096) * 256 + tid;
        int r = i / FP, c = i - r * FP;
        WfP[i] = (c < FUSED_IN) ? Wf[(long)r * FUSED_IN + c] : 0.f;
    } else if (bx < 6464) {
        int i = (bx - 6336) * 256 + tid;
        hzero[i] = 0.f;
    } else if (bx < 6472) {
        int i = (bx - 6464) * 256 + tid;
        bsum[i] = bih[i] + bhh[i];
    } else if (bx < 6504) {
        // W1 fragment-major bf16: frag[(jt*8+kt)*64+lane][e] = W1[jt*16+(lane&15)][kt*32+(lane>>4)*8+e]
        int job = (bx - 6472) * 256 + tid;     // < 8192
        int jt = job >> 9, rem = job & 511, kt = rem >> 6, lane = rem & 63;
        int j = jt * 16 + (lane & 15), k0 = kt * 32 + (lane >> 4) * 8;
        const float* src = &W1[(long)j * 256 + k0];
        uint4 p;
        p.x = pk2(src[0], src[1]); p.y = pk2(src[2], src[3]);
        p.z = pk2(src[4], src[5]); p.w = pk2(src[6], src[7]);
        W1f[job] = p;
    } else {
        // A fragment-major bf16, zero-padded to [112 m][128 n]
        int job = (bx - 6504) * 256 + tid;     // < 1792
        int mt = job >> 8, rem = job & 255, kt = rem >> 6, lane = rem & 63;
        int m = mt * 16 + (lane & 15), n0 = kt * 32 + (lane >> 4) * 8;
        float h[8];
#pragma unroll
        for (int e = 0; e < 8; ++e)
            h[e] = (m < 100 && n0 + e < 100) ? A[m * 100 + n0 + e] : 0.f;
        uint4 p;
        p.x = pk2(h[0], h[1]); p.y = pk2(h[2], h[3]);
        p.z = pk2(h[4], h[5]); p.w = pk2(h[6], h[7]);
        Af[job] = p;
    }
}

// fused concat, padded to FP
__global__ void k_fused(const float* __restrict__ feats, const float* __restrict__ ge,
                        const float* __restrict__ ae, const float* __restrict__ gcn,
                        float* __restrict__ fused)
{
    int i = blockIdx.x * 256 + threadIdx.x;
    int b = i / FP, c = i - b * FP;
    float v = 0.f;
    if (c < 512) v = feats[(long)b * 512 + c];
    else if (c < 576) v = ge[(long)b * 64 + (c - 512)];
    else if (c < 586) v = ae[(long)b * 10 + (c - 576)];
    else if (c < 1098) v = gcn[(long)b * 512 + (c - 586)];
    fused[i] = v;
}

__device__ __forceinline__ float sigf(float x) { return 1.f / (1.f + __expf(-x)); }

__global__ __launch_bounds__(256)
void lstm_step2(const float* __restrict__ xWih,
                const float4* __restrict__ W4,
                const float* __restrict__ hPrev, const float* __restrict__ cPrev,
                float* __restrict__ hNext, float* __restrict__ cNext,
                float* __restrict__ sf, int t)
{
    __shared__ float hlds[512 * 17];
    __shared__ float4 pex[256];
    const int tid = threadIdx.x;
    const float4* hp4 = (const float4*)hPrev;
#pragma unroll
    for (int l = 0; l < 8; ++l) {
        int i4 = tid + l * 256;
        int bb = i4 >> 7, hq = i4 & 127;
        float4 h4 = hp4[i4];
        int hh0 = hq * 4;
        hlds[(hh0 + 0) * 17 + bb] = h4.x;
        hlds[(hh0 + 1) * 17 + bb] = h4.y;
        hlds[(hh0 + 2) * 17 + bb] = h4.z;
        hlds[(hh0 + 3) * 17 + bb] = h4.w;
    }
    __syncthreads();
    const int b = tid & 15, j2 = (tid >> 4) & 1, ks = tid >> 5;
    const int jh = blockIdx.x * 2 + j2;
    float ai = 0.f, af = 0.f, ag = 0.f, ao = 0.f;
    const float4* wcol = W4 + jh;
    int hh = ks * 64;
#pragma unroll 4
    for (int r = 0; r < 64; ++r, ++hh) {
        float4 w = wcol[(long)hh * 512];
        float hp = hlds[hh * 17 + b];
        ai = fmaf(w.x, hp, ai);
        af = fmaf(w.y, hp, af);
        ag = fmaf(w.z, hp, ag);
        ao = fmaf(w.w, hp, ao);
    }
    pex[tid] = make_float4(ai, af, ag, ao);
    __syncthreads();
    if (tid < 32) {
        int fb = tid & 15, fj = tid >> 4;
        float gi = 0.f, gf = 0.f, gg = 0.f, go = 0.f;
#pragma unroll
        for (int k = 0; k < 8; ++k) {
            float4 p = pex[k * 32 + fj * 16 + fb];
            gi += p.x; gf += p.y; gg += p.z; go += p.w;
        }
        int jhf = blockIdx.x * 2 + fj;
        const float* xw = xWih + (long)(fb * T + t) * 2048;
        gi += xw[jhf]; gf += xw[512 + jhf]; gg += xw[1024 + jhf]; go += xw[1536 + jhf];
        float cp = cPrev[fb * 512 + jhf];
        float cn = sigf(gf) * cp + sigf(gi) * tanhf(gg);
        float hn = sigf(go) * tanhf(cn);
        cNext[fb * 512 + jhf] = cn;
        hNext[fb * 512 + jhf] = hn;
        sf[(long)(fb * T + t) * 512 + jhf] = hn;
    }
}

__global__ void k_copy_hc(const float* __restrict__ h, const float* __restrict__ c,
                          float* __restrict__ out)
{
    int i = blockIdx.x * 256 + threadIdx.x;
    out[3584 + i] = h[i];
    out[11776 + i] = c[i];
}

// ---------------- host ----------------
static inline void g32(hipStream_t st, const float* A, int lda, const float* B, int ldb,
                       float* C, int ldc, const float* bias, int M, int N, int K, bool relu)
{
    dim3 g((N + 63) / 64, (M + 31) / 32), blk(128);
    if (relu) hipLaunchKernelGGL((gemm32<true>), g, blk, 0, st, A, lda, B, ldb, C, ldc, bias, M, N, K);
    else      hipLaunchKernelGGL((gemm32<false>), g, blk, 0, st, A, lda, B, ldb, C, ldc, bias, M, N, K);
}
static inline void gnt(hipStream_t st, const float* A, int lda, const float* B, int ldb,
                       float* C, int ldc, const float* bias, int M, int N, int K, bool relu)
{
    dim3 g((N + BN - 1) / BN, (M + BM - 1) / BM), blk(256);
    if (relu) hipLaunchKernelGGL((gemm_nt<true>), g, blk, 0, st, A, lda, B, ldb, C, ldc, bias, M, N, K);
    else      hipLaunchKernelGGL((gemm_nt<false>), g, blk, 0, st, A, lda, B, ldb, C, ldc, bias, M, N, K);
}

extern "C" void kernel_launch(void* const* d_in, const int* in_sizes, int n_in,
                              void* d_out, int out_size, void* d_ws, size_t ws_size,
                              hipStream_t stream)
{
    const float* target = (const float*)d_in[0];
    const float* input_ = (const float*)d_in[1];
    const float* aprob  = (const float*)d_in[2];
    const float* Adj    = (const float*)d_in[3];
    const float* aglove = (const float*)d_in[4];
    const float* Wword  = (const float*)d_in[5];
    const float* bword  = (const float*)d_in[6];
    const float* Wg     = (const float*)d_in[7];
    const float* bg     = (const float*)d_in[8];
    const float* Wa     = (const float*)d_in[9];
    const float* ba     = (const float*)d_in[10];
    const float* W0     = (const float*)d_in[11];
    const float* W1     = (const float*)d_in[12];
    const float* W2     = (const float*)d_in[13];
    const float* Wfm    = (const float*)d_in[14];
    const float* bfm    = (const float*)d_in[15];
    const float* Wf     = (const float*)d_in[16];
    const float* bf     = (const float*)d_in[17];
    const float* Wih    = (const float*)d_in[18];
    const float* Whh    = (const float*)d_in[19];
    const float* bih    = (const float*)d_in[20];
    const float* bhh    = (const float*)d_in[21];
    const float* Wa1    = (const float*)d_in[22];
    const float* ba1    = (const float*)d_in[23];
    const float* Wa2    = (const float*)d_in[24];
    const float* ba2    = (const float*)d_in[25];
    const float* Wc1    = (const float*)d_in[26];
    const float* bc1    = (const float*)d_in[27];
    const float* Wc2    = (const float*)d_in[28];
    const float* bc2    = (const float*)d_in[29];

    float* ws = (float*)d_ws;
    float* out = (float*)d_out;

    size_t off = 0;
    auto alloc = [&](size_t n) { size_t r = off; off += (n + 255) & ~(size_t)255; return r; };
    float* glove_e = ws + alloc(512 * 64);
    float* act_e   = ws + alloc(512 * 10);
    float* u       = ws + alloc(512 * 256);
    float* word    = ws + alloc(100 * 64);
    float* Aw      = ws + alloc(100 * 64);
    float* rowsum  = ws + alloc(128);
    float* v       = ws + alloc(100 * 256);
    float* x3      = ws + alloc(512 * 100);
    float* gcn_e   = ws + alloc(512 * 512);
    float* fused   = ws + alloc((size_t)512 * FP);
    float* WfP     = ws + alloc((size_t)512 * FP);
    float* outf    = ws + alloc(512 * 512);
    float* bsum    = ws + alloc(2048);
    float* xWih    = ws + alloc((size_t)512 * 2048);
    float* WhhT2   = ws + alloc((size_t)512 * 2048);
    float* hA      = ws + alloc(BSZ * Hh);
    float* cA      = ws + alloc(BSZ * Hh);
    float* hB      = ws + alloc(BSZ * Hh);
    float* cB      = ws + alloc(BSZ * Hh);
    float* sf      = ws + alloc(512 * 512);
    float* ah      = ws + alloc(512 * 128);
    float* ch      = ws + alloc(512 * 128);
    float* W1frag  = ws + alloc(32768);   // 65536 bf16 = 128 KB
    float* Afrag   = ws + alloc(7168);    // 14336 bf16 = 28 KB
    (void)ws_size; (void)in_sizes; (void)n_in; (void)out_size;

    const float* feats = input_; // [512,512]

    // --- preprocessing (WhhT2, WfP, zero h/c, bsum, W1/A bf16 frags) ---
    hipLaunchKernelGGL(k_prep, dim3(6511), dim3(256), 0, stream,
                       Whh, WhhT2, Wf, WfP, hA, bih, bhh, bsum,
                       W1, (uint4*)W1frag, Adj, (uint4*)Afrag);

    // --- embeddings & separable precomputes ---
    g32(stream, target, GLOVE, Wg, GLOVE, glove_e, 64, bg, 512, 64, GLOVE, true);
    gnt(stream, aprob, ASPACE, Wa, ASPACE, act_e, 10, ba, 512, 10, ASPACE, true);
    g32(stream, feats, 512, W0, 576, u, 256, nullptr, 512, 256, 512, false);
    g32(stream, aglove, GLOVE, Wword, GLOVE, word, 64, bword, 100, 64, GLOVE, false);
    hipLaunchKernelGGL(k_aw_rowsum, dim3(26), dim3(256), 0, stream, Adj, word, Aw, rowsum);
    g32(stream, Aw, 64, W0 + 512, 576, v, 256, nullptr, 100, 256, 64, false);

    // --- fused GCN middle (MFMA) ---
    hipLaunchKernelGGL(gcn_fused, dim3(Bt), dim3(256), 0, stream,
                       u, v, rowsum, Adj, (const bf16x8*)W1frag, (const bf16x8*)Afrag, W2, x3);
    g32(stream, x3, 100, Wfm, 100, gcn_e, 512, bfm, 512, 512, 100, false);

    // --- fuse + trunk ---
    hipLaunchKernelGGL(k_fused, dim3(512 * FP / 256), dim3(256), 0, stream,
                       feats, glove_e, act_e, gcn_e, fused);
    g32(stream, fused, FP, WfP, FP, outf, 512, bf, 512, 512, FP, true);
    g32(stream, outf, 512, Wih, 512, xWih, 2048, bsum, 512, 2048, 512, false);

    // --- LSTM recurrence ---
    for (int t = 0; t < T; ++t) {
        const float* hp = (t & 1) ? hB : hA;
        const float* cp = (t & 1) ? cB : cA;
        float* hn = (t & 1) ? hA : hB;
        float* cn = (t & 1) ? cA : cB;
        hipLaunchKernelGGL(lstm_step2, dim3(256), dim3(256), 0, stream,
                           xWih, (const float4*)WhhT2, hp, cp, hn, cn, sf, t);
    }

    // --- heads ---
    g32(stream, sf, 512, Wa1, 512, ah, 128, ba1, 512, 128, 512, true);
    gnt(stream, ah, 128, Wa2, 128, out, 6, ba2, 512, 6, 128, true);
    g32(stream, sf, 512, Wc1, 512, ch, 128, bc1, 512, 128, 512, true);
    gnt(stream, ch, 128, Wc2, 128, out + 3072, 1, bc2, 512, 1, 128, true);
    hipLaunchKernelGGL(k_copy_hc, dim3(32), dim3(256), 0, stream, hA, cA, out);
}

// Round 6
// 371.477 us; speedup vs baseline: 4.8410x; 1.7778x over previous
//
#include <hip/hip_runtime.h>
#include <cmath>

// ---------------- problem constants ----------------
constexpr int BSZ = 16, T = 32, NOBJ = 100;
constexpr int GLOVE = 300, GEMB = 64, ADIM = 10, GCN_DIM = 512, Hh = 512, ASPACE = 6, RES = 512;
constexpr int Bt = BSZ * T;          // 512
constexpr int FUSED_IN = RES + GEMB + ADIM + GCN_DIM; // 1098
constexpr int FP = 1120;             // padded fused width

typedef __attribute__((ext_vector_type(8))) short bf16x8;
typedef __attribute__((ext_vector_type(4))) float f32x4;

__device__ __forceinline__ unsigned short f2bf(float f) {
    unsigned u = __float_as_uint(f);
    return (unsigned short)((u + 0x7FFFu + ((u >> 16) & 1u)) >> 16);
}
__device__ __forceinline__ unsigned pk2(float a, float b) {
    return (unsigned)f2bf(a) | ((unsigned)f2bf(b) << 16);
}

// ---------------- mgemm: C = A @ B^T (+bias)(relu), bf16 in, fp32 acc ----------------
// A [M,K] bf16 row-major lda; B [N,K] bf16 ldb; no LDS, no syncs.
// Block 256 = 4 waves; wave w computes rows [by*64+w*16, +16) x cols [bx*64, +64).
// Requires M%64==0, N%64==0, K%32==0, lda/ldb %8==0.
// Frag maps (HW-validated in round-4 gcn_fused): A row=l&15,k=(l>>4)*8+e;
// B n=l&15, same k; D col=l&15, row=(l>>4)*4+r.
template<bool RELU, int OMODE>  // OMODE: 0=fp32 out, 1=bf16 out
__global__ __launch_bounds__(256)
void mgemm(const unsigned short* __restrict__ A, int lda,
           const unsigned short* __restrict__ B, int ldb,
           float* __restrict__ Cf, unsigned short* __restrict__ Cb, int ldc,
           const float* __restrict__ bias, int K)
{
    const int tid = threadIdx.x;
    const int l = tid & 63, wv = tid >> 6;
    const int m0 = blockIdx.y * 64 + wv * 16;
    const int n0 = blockIdx.x * 64;
    const int lr = l & 15, kg = l >> 4;
    const unsigned short* ap = A + (long)(m0 + lr) * lda + kg * 8;
    const unsigned short* bp = B + (long)(n0 + lr) * ldb + kg * 8;
    f32x4 acc0 = (f32x4){0.f, 0.f, 0.f, 0.f};
    f32x4 acc1 = acc0, acc2 = acc0, acc3 = acc0;
    for (int k0 = 0; k0 < K; k0 += 32) {
        bf16x8 a  = *(const bf16x8*)(ap + k0);
        bf16x8 b0 = *(const bf16x8*)(bp + k0);
        bf16x8 b1 = *(const bf16x8*)(bp + 16 * ldb + k0);
        bf16x8 b2 = *(const bf16x8*)(bp + 32 * ldb + k0);
        bf16x8 b3 = *(const bf16x8*)(bp + 48 * ldb + k0);
        acc0 = __builtin_amdgcn_mfma_f32_16x16x32_bf16(a, b0, acc0, 0, 0, 0);
        acc1 = __builtin_amdgcn_mfma_f32_16x16x32_bf16(a, b1, acc1, 0, 0, 0);
        acc2 = __builtin_amdgcn_mfma_f32_16x16x32_bf16(a, b2, acc2, 0, 0, 0);
        acc3 = __builtin_amdgcn_mfma_f32_16x16x32_bf16(a, b3, acc3, 0, 0, 0);
    }
    f32x4 av[4] = {acc0, acc1, acc2, acc3};
#pragma unroll
    for (int nf = 0; nf < 4; ++nf) {
        int n = n0 + nf * 16 + lr;
        float bs = bias ? bias[n] : 0.f;
#pragma unroll
        for (int r = 0; r < 4; ++r) {
            float val = av[nf][r] + bs;
            if (RELU) val = fmaxf(val, 0.f);
            long idx = (long)(m0 + kg * 4 + r) * ldc + n;
            if (OMODE == 0) Cf[idx] = val;
            else            Cb[idx] = f2bf(val);
        }
    }
}

// ---------------- fp32 GEMMs for the tiny ragged cases (word, v, act_e) ----------------
template<bool RELU>
__global__ __launch_bounds__(128)
void gemm32(const float* __restrict__ A, int lda,
            const float* __restrict__ B, int ldb,
            float* __restrict__ C, int ldc,
            const float* __restrict__ bias, int M, int N, int K)
{
    __shared__ float As[32][36];
    __shared__ float Bs[32][68];
    const int tid = threadIdx.x;
    const int m0 = blockIdx.y * 32, n0 = blockIdx.x * 64;
    const int mi = tid >> 4, ni = tid & 15;
    float acc[4][4] = {};
    for (int k0 = 0; k0 < K; k0 += 32) {
        __syncthreads();
#pragma unroll
        for (int l = 0; l < 2; ++l) {
            int e = tid + l * 128;
            int row = e >> 3, kq = (e & 7) << 2;
            float4 va = make_float4(0.f, 0.f, 0.f, 0.f);
            if (m0 + row < M && k0 + kq < K)
                va = *(const float4*)&A[(long)(m0 + row) * lda + k0 + kq];
            As[kq + 0][row] = va.x; As[kq + 1][row] = va.y;
            As[kq + 2][row] = va.z; As[kq + 3][row] = va.w;
        }
#pragma unroll
        for (int l = 0; l < 4; ++l) {
            int e = tid + l * 128;
            int row = e >> 3, kq = (e & 7) << 2;
            float4 vb = make_float4(0.f, 0.f, 0.f, 0.f);
            if (n0 + row < N && k0 + kq < K)
                vb = *(const float4*)&B[(long)(n0 + row) * ldb + k0 + kq];
            Bs[kq + 0][row] = vb.x; Bs[kq + 1][row] = vb.y;
            Bs[kq + 2][row] = vb.z; Bs[kq + 3][row] = vb.w;
        }
        __syncthreads();
#pragma unroll
        for (int k = 0; k < 32; ++k) {
            float4 a4 = *(const float4*)&As[k][4 * mi];
            float4 b4 = *(const float4*)&Bs[k][4 * ni];
            acc[0][0] = fmaf(a4.x, b4.x, acc[0][0]); acc[0][1] = fmaf(a4.x, b4.y, acc[0][1]);
            acc[0][2] = fmaf(a4.x, b4.z, acc[0][2]); acc[0][3] = fmaf(a4.x, b4.w, acc[0][3]);
            acc[1][0] = fmaf(a4.y, b4.x, acc[1][0]); acc[1][1] = fmaf(a4.y, b4.y, acc[1][1]);
            acc[1][2] = fmaf(a4.y, b4.z, acc[1][2]); acc[1][3] = fmaf(a4.y, b4.w, acc[1][3]);
            acc[2][0] = fmaf(a4.z, b4.x, acc[2][0]); acc[2][1] = fmaf(a4.z, b4.y, acc[2][1]);
            acc[2][2] = fmaf(a4.z, b4.z, acc[2][2]); acc[2][3] = fmaf(a4.z, b4.w, acc[2][3]);
            acc[3][0] = fmaf(a4.w, b4.x, acc[3][0]); acc[3][1] = fmaf(a4.w, b4.y, acc[3][1]);
            acc[3][2] = fmaf(a4.w, b4.z, acc[3][2]); acc[3][3] = fmaf(a4.w, b4.w, acc[3][3]);
        }
    }
    const int n = n0 + 4 * ni;
    if (n >= N) return;
    float4 bv = make_float4(0.f, 0.f, 0.f, 0.f);
    if (bias) bv = *(const float4*)&bias[n];
#pragma unroll
    for (int r = 0; r < 4; ++r) {
        int m = m0 + 4 * mi + r;
        if (m >= M) continue;
        float4 v;
        v.x = acc[r][0] + bv.x; v.y = acc[r][1] + bv.y;
        v.z = acc[r][2] + bv.z; v.w = acc[r][3] + bv.w;
        if (RELU) {
            v.x = fmaxf(v.x, 0.f); v.y = fmaxf(v.y, 0.f);
            v.z = fmaxf(v.z, 0.f); v.w = fmaxf(v.w, 0.f);
        }
        *(float4*)&C[(long)m * ldc + n] = v;
    }
}

constexpr int BM = 64, BN = 64, BK = 16;
template<bool RELU>
__global__ __launch_bounds__(256)
void gemm_nt(const float* __restrict__ A, int lda,
             const float* __restrict__ Bp, int ldb,
             float* __restrict__ C, int ldc,
             const float* __restrict__ bias, int M, int N, int K)
{
    const int m0 = blockIdx.y * BM, n0 = blockIdx.x * BN;
    __shared__ float As[BK][BM + 1];
    __shared__ float Bs[BK][BN + 1];
    const int tid = threadIdx.x;
    const int lo = tid * 4;
    const int lm = lo >> 4;
    const int lk = lo & 15;
    const int row = (tid >> 4) * 4, col = (tid & 15) * 4;
    float acc[4][4] = {};
    for (int k0 = 0; k0 < K; k0 += BK) {
#pragma unroll
        for (int e = 0; e < 4; ++e) {
            int k = lk + e;
            float va = 0.f, vb = 0.f;
            if (k0 + k < K) {
                if (m0 + lm < M) va = A[(long)(m0 + lm) * lda + k0 + k];
                if (n0 + lm < N) vb = Bp[(long)(n0 + lm) * ldb + k0 + k];
            }
            As[k][lm] = va;
            Bs[k][lm] = vb;
        }
        __syncthreads();
#pragma unroll
        for (int k = 0; k < BK; ++k) {
            float a0 = As[k][row], a1 = As[k][row + 1], a2 = As[k][row + 2], a3 = As[k][row + 3];
            float b0 = Bs[k][col], b1 = Bs[k][col + 1], b2 = Bs[k][col + 2], b3 = Bs[k][col + 3];
            acc[0][0] += a0 * b0; acc[0][1] += a0 * b1; acc[0][2] += a0 * b2; acc[0][3] += a0 * b3;
            acc[1][0] += a1 * b0; acc[1][1] += a1 * b1; acc[1][2] += a1 * b2; acc[1][3] += a1 * b3;
            acc[2][0] += a2 * b0; acc[2][1] += a2 * b1; acc[2][2] += a2 * b2; acc[2][3] += a2 * b3;
            acc[3][0] += a3 * b0; acc[3][1] += a3 * b1; acc[3][2] += a3 * b2; acc[3][3] += a3 * b3;
        }
        __syncthreads();
    }
#pragma unroll
    for (int i = 0; i < 4; ++i) {
        int m = m0 + row + i;
        if (m >= M) continue;
#pragma unroll
        for (int j = 0; j < 4; ++j) {
            int n = n0 + col + j;
            if (n >= N) continue;
            float v = acc[i][j];
            if (bias) v += bias[n];
            if (RELU) v = fmaxf(v, 0.f);
            C[(long)m * ldc + n] = v;
        }
    }
}

// ---------------- fused GCN middle, MFMA (unchanged core; x3 out -> padded bf16) ----------------
__global__ __launch_bounds__(256, 2)
void gcn_fused(const float* __restrict__ u,      // [512,256]
               const float* __restrict__ v,      // [100,256]
               const float* __restrict__ rowsum, // [100]
               const float* __restrict__ Aglob,  // [100,100] fp32
               const bf16x8* __restrict__ W1f,   // [16jt][8kt][64lane] frags
               const bf16x8* __restrict__ Af,    // [7mt][4kt][64lane] frags
               const float* __restrict__ w2,     // [256]
               unsigned short* __restrict__ x3b) // [512,128] bf16, cols >=100 zero
{
    __shared__ unsigned short X1s[112 * 40];
    __shared__ unsigned short Z1Ts[128 * 136];
    __shared__ float u_lds[256];
    __shared__ float rs_lds[112];
    __shared__ float w2l[256];
    __shared__ float spart[4][112];
    __shared__ float sl[112];

    const int b = blockIdx.x, tid = threadIdx.x;
    const int l = tid & 63, wv = tid >> 6;
    const int lrow = l & 15, kg = l >> 4;

    u_lds[tid] = u[(long)b * 256 + tid];
    w2l[tid] = w2[tid];
    if (tid < 112) rs_lds[tid] = (tid < 100) ? rowsum[tid] : 0.f;
    if (tid < 128) {
        uint4 z = make_uint4(0, 0, 0, 0);
        *(uint4*)&Z1Ts[tid * 136 + 112] = z;
        *(uint4*)&Z1Ts[tid * 136 + 120] = z;
    }
    if (tid < 28) x3b[(long)b * 128 + 100 + tid] = 0;

    float sacc[7][4];
#pragma unroll
    for (int mt = 0; mt < 7; ++mt)
#pragma unroll
        for (int r = 0; r < 4; ++r) sacc[mt][r] = 0.f;

    for (int half = 0; half < 2; ++half) {
        f32x4 acc1[7][2];
#pragma unroll
        for (int mt = 0; mt < 7; ++mt)
#pragma unroll
            for (int jtl = 0; jtl < 2; ++jtl) acc1[mt][jtl] = (f32x4){0.f, 0.f, 0.f, 0.f};

        for (int kt = 0; kt < 8; ++kt) {
            __syncthreads();
            if (tid < 224) {
                int n = tid >> 1, kh = (tid & 1) << 4;
                int kb = kt * 32 + kh;
                uint4 p0 = make_uint4(0, 0, 0, 0), p1 = make_uint4(0, 0, 0, 0);
                if (n < 100) {
                    float rsn = rs_lds[n];
                    const float4* vp = (const float4*)&v[n * 256 + kb];
                    float4 u0 = *(const float4*)&u_lds[kb];
                    float4 u1 = *(const float4*)&u_lds[kb + 4];
                    float4 u2 = *(const float4*)&u_lds[kb + 8];
                    float4 u3 = *(const float4*)&u_lds[kb + 12];
                    float4 v0 = vp[0], v1 = vp[1], v2 = vp[2], v3 = vp[3];
                    float x0 = fmaxf(fmaf(rsn, u0.x, v0.x), 0.f), x1 = fmaxf(fmaf(rsn, u0.y, v0.y), 0.f);
                    float x2 = fmaxf(fmaf(rsn, u0.z, v0.z), 0.f), x3v = fmaxf(fmaf(rsn, u0.w, v0.w), 0.f);
                    float x4 = fmaxf(fmaf(rsn, u1.x, v1.x), 0.f), x5 = fmaxf(fmaf(rsn, u1.y, v1.y), 0.f);
                    float x6 = fmaxf(fmaf(rsn, u1.z, v1.z), 0.f), x7 = fmaxf(fmaf(rsn, u1.w, v1.w), 0.f);
                    float x8 = fmaxf(fmaf(rsn, u2.x, v2.x), 0.f), x9 = fmaxf(fmaf(rsn, u2.y, v2.y), 0.f);
                    float xa = fmaxf(fmaf(rsn, u2.z, v2.z), 0.f), xb = fmaxf(fmaf(rsn, u2.w, v2.w), 0.f);
                    float xc = fmaxf(fmaf(rsn, u3.x, v3.x), 0.f), xd = fmaxf(fmaf(rsn, u3.y, v3.y), 0.f);
                    float xe = fmaxf(fmaf(rsn, u3.z, v3.z), 0.f), xf = fmaxf(fmaf(rsn, u3.w, v3.w), 0.f);
                    p0 = make_uint4(pk2(x0, x1), pk2(x2, x3v), pk2(x4, x5), pk2(x6, x7));
                    p1 = make_uint4(pk2(x8, x9), pk2(xa, xb), pk2(xc, xd), pk2(xe, xf));
                }
                *(uint4*)&X1s[n * 40 + kh] = p0;
                *(uint4*)&X1s[n * 40 + kh + 8] = p1;
            }
            __syncthreads();
            bf16x8 af[7];
#pragma unroll
            for (int mt = 0; mt < 7; ++mt)
                af[mt] = *(const bf16x8*)&X1s[(mt * 16 + lrow) * 40 + kg * 8];
#pragma unroll
            for (int jtl = 0; jtl < 2; ++jtl) {
                int jt = half * 8 + wv * 2 + jtl;
                bf16x8 bfr = W1f[(jt * 8 + kt) * 64 + l];
#pragma unroll
                for (int mt = 0; mt < 7; ++mt)
                    acc1[mt][jtl] = __builtin_amdgcn_mfma_f32_16x16x32_bf16(af[mt], bfr, acc1[mt][jtl], 0, 0, 0);
            }
        }

#pragma unroll
        for (int mt = 0; mt < 7; ++mt)
#pragma unroll
            for (int jtl = 0; jtl < 2; ++jtl) {
                int jloc = (wv * 2 + jtl) * 16 + lrow;
                f32x4 a = acc1[mt][jtl];
                uint2 zz;
                zz.x = pk2(a[0], a[1]);
                zz.y = pk2(a[2], a[3]);
                *(uint2*)&Z1Ts[jloc * 136 + mt * 16 + kg * 4] = zz;
            }

        bf16x8 bz[2][4];
#pragma unroll
        for (int jtl = 0; jtl < 2; ++jtl)
#pragma unroll
            for (int k2 = 0; k2 < 4; ++k2)
                bz[jtl][k2] = *(const bf16x8*)&Z1Ts[((wv * 2 + jtl) * 16 + lrow) * 136 + k2 * 32 + kg * 8];
#pragma unroll
        for (int mt = 0; mt < 7; ++mt) {
            bf16x8 aA[4];
#pragma unroll
            for (int k2 = 0; k2 < 4; ++k2) aA[k2] = Af[(mt * 4 + k2) * 64 + l];
#pragma unroll
            for (int jtl = 0; jtl < 2; ++jtl) {
                f32x4 p = (f32x4){0.f, 0.f, 0.f, 0.f};
#pragma unroll
                for (int k2 = 0; k2 < 4; ++k2)
                    p = __builtin_amdgcn_mfma_f32_16x16x32_bf16(aA[k2], bz[jtl][k2], p, 0, 0, 0);
                float w2j = w2l[half * 128 + (wv * 2 + jtl) * 16 + lrow];
#pragma unroll
                for (int r = 0; r < 4; ++r)
                    sacc[mt][r] = fmaf(fmaxf(p[r], 0.f), w2j, sacc[mt][r]);
            }
        }
    }

#pragma unroll
    for (int mt = 0; mt < 7; ++mt) {
        float s0 = sacc[mt][0], s1 = sacc[mt][1], s2 = sacc[mt][2], s3 = sacc[mt][3];
#pragma unroll
        for (int off = 1; off < 16; off <<= 1) {
            s0 += __shfl_xor(s0, off);
            s1 += __shfl_xor(s1, off);
            s2 += __shfl_xor(s2, off);
            s3 += __shfl_xor(s3, off);
        }
        if (lrow == 0) {
            int m = mt * 16 + kg * 4;
            spart[wv][m + 0] = s0; spart[wv][m + 1] = s1;
            spart[wv][m + 2] = s2; spart[wv][m + 3] = s3;
        }
    }
    __syncthreads();
    if (tid < 112)
        sl[tid] = spart[0][tid] + spart[1][tid] + spart[2][tid] + spart[3][tid];
    __syncthreads();

    float sv0 = (l < 100) ? sl[l] : 0.f;
    float sv1 = (l + 64 < 100) ? sl[l + 64] : 0.f;
#pragma unroll 5
    for (int i = 0; i < 25; ++i) {
        int n = i * 4 + wv;
        float a0 = (l < 100) ? Aglob[n * 100 + l] : 0.f;
        float a1 = (l + 64 < 100) ? Aglob[n * 100 + l + 64] : 0.f;
        float p = a0 * sv0 + a1 * sv1;
#pragma unroll
        for (int off = 32; off; off >>= 1) p += __shfl_xor(p, off);
        if (l == 0) x3b[(long)b * 128 + n] = f2bf(fmaxf(p, 0.f));
    }
}

// ---------------- glue kernels ----------------
__global__ void k_aw_rowsum(const float* __restrict__ A, const float* __restrict__ word,
                            float* __restrict__ Aw, float* __restrict__ rowsum)
{
    int i = blockIdx.x * 256 + threadIdx.x;
    if (i < 6400) {
        int n = i / 64, k = i % 64;
        float s = 0.f;
        for (int m = 0; m < 100; ++m) s += A[n * 100 + m] * word[m * 64 + k];
        Aw[i] = s;
    } else if (i < 6500) {
        int n = i - 6400;
        float s = 0.f;
        for (int m = 0; m < 100; ++m) s += A[n * 100 + m];
        rowsum[n] = s;
    }
}

// big preprocessing kernel: all weight/activation bf16 conversions + transposes + zeros.
// segment table (blocks of 256 threads):
//  [0,4096)      WhhT2 fp32 transpose           1048576
//  [4096,6336)   WfP_bf  [512][1120] pad        573440
//  [6336,10432)  Wih_bf  [2048][512]            1048576
//  [10432,10944) Whd_bf  [256][512] Wa1|Wc1     131072
//  [10944,10945) bhd[256] = ba1|bc1
//  [10945,11025) Wg_bf   [64][320] pad          20480
//  [11025,11537) W0a_bf  [256][512] (W0 cols 0-511)  131072
//  [11537,11793) Wfm_bf  [512][128] pad         65536
//  [11793,12433) tgt_bf  [512][320] pad         163840
//  [12433,13457) feats_bf[512][512]             262144
//  [13457,13585) zero h/c                       32768
//  [13585,13593) bsum                           2048
//  [13593,13625) W1frag                         8192 jobs
//  [13625,13632) Afrag                          1792 jobs
__global__ void k_prep(const float* __restrict__ Whh, float* __restrict__ WhhT2,
                       const float* __restrict__ Wf, unsigned short* __restrict__ WfPb,
                       const float* __restrict__ Wih, unsigned short* __restrict__ Wihb,
                       const float* __restrict__ Wa1, const float* __restrict__ Wc1,
                       unsigned short* __restrict__ Whdb,
                       const float* __restrict__ ba1, const float* __restrict__ bc1,
                       float* __restrict__ bhd,
                       const float* __restrict__ Wg, unsigned short* __restrict__ Wgb,
                       const float* __restrict__ W0, unsigned short* __restrict__ W0ab,
                       const float* __restrict__ Wfm, unsigned short* __restrict__ Wfmb,
                       const float* __restrict__ target, unsigned short* __restrict__ tgtb,
                       const float* __restrict__ feats, unsigned short* __restrict__ featsb,
                       float* __restrict__ hzero,
                       const float* __restrict__ bih, const float* __restrict__ bhh,
                       float* __restrict__ bsum,
                       const float* __restrict__ W1, uint4* __restrict__ W1f,
                       const float* __restrict__ A, uint4* __restrict__ Af)
{
    int bx = blockIdx.x, tid = threadIdx.x;
    if (bx < 4096) {
        int i = bx * 256 + tid;
        int hh = i >> 11, rem = i & 2047, jh = rem >> 2, g = rem & 3;
        WhhT2[i] = Whh[(long)(g * 512 + jh) * 512 + hh];
    } else if (bx < 6336) {
        int i = (bx - 4096) * 256 + tid;
        int r = i / FP, c = i - r * FP;
        WfPb[i] = f2bf(c < FUSED_IN ? Wf[(long)r * FUSED_IN + c] : 0.f);
    } else if (bx < 10432) {
        int i = (bx - 6336) * 256 + tid;
        Wihb[i] = f2bf(Wih[i]);
    } else if (bx < 10944) {
        int i = (bx - 10432) * 256 + tid;
        int r = i >> 9, c = i & 511;
        Whdb[i] = f2bf(r < 128 ? Wa1[r * 512 + c] : Wc1[(r - 128) * 512 + c]);
    } else if (bx < 10945) {
        bhd[tid] = (tid < 128) ? ba1[tid] : bc1[tid - 128];
    } else if (bx < 11025) {
        int i = (bx - 10945) * 256 + tid;
        int r = i / 320, c = i - r * 320;
        Wgb[i] = f2bf(c < GLOVE ? Wg[r * GLOVE + c] : 0.f);
    } else if (bx < 11537) {
        int i = (bx - 11025) * 256 + tid;
        int r = i >> 9, c = i & 511;
        W0ab[i] = f2bf(W0[(long)r * 576 + c]);
    } else if (bx < 11793) {
        int i = (bx - 11537) * 256 + tid;
        int r = i >> 7, c = i & 127;
        Wfmb[i] = f2bf(c < 100 ? Wfm[r * 100 + c] : 0.f);
    } else if (bx < 12433) {
        int i = (bx - 11793) * 256 + tid;
        int r = i / 320, c = i - r * 320;
        tgtb[i] = f2bf(c < GLOVE ? target[(long)r * GLOVE + c] : 0.f);
    } else if (bx < 13457) {
        int i = (bx - 12433) * 256 + tid;
        featsb[i] = f2bf(feats[i]);
    } else if (bx < 13585) {
        int i = (bx - 13457) * 256 + tid;
        hzero[i] = 0.f;
    } else if (bx < 13593) {
        int i = (bx - 13585) * 256 + tid;
        bsum[i] = bih[i] + bhh[i];
    } else if (bx < 13625) {
        int job = (bx - 13593) * 256 + tid;     // < 8192
        int jt = job >> 9, rem = job & 511, kt = rem >> 6, lane = rem & 63;
        int j = jt * 16 + (lane & 15), k0 = kt * 32 + (lane >> 4) * 8;
        const float* src = &W1[(long)j * 256 + k0];
        uint4 p;
        p.x = pk2(src[0], src[1]); p.y = pk2(src[2], src[3]);
        p.z = pk2(src[4], src[5]); p.w = pk2(src[6], src[7]);
        W1f[job] = p;
    } else {
        int job = (bx - 13625) * 256 + tid;     // < 1792
        int mt = job >> 8, rem = job & 255, kt = rem >> 6, lane = rem & 63;
        int m = mt * 16 + (lane & 15), n0 = kt * 32 + (lane >> 4) * 8;
        float h[8];
#pragma unroll
        for (int e = 0; e < 8; ++e)
            h[e] = (m < 100 && n0 + e < 100) ? A[m * 100 + n0 + e] : 0.f;
        uint4 p;
        p.x = pk2(h[0], h[1]); p.y = pk2(h[2], h[3]);
        p.z = pk2(h[4], h[5]); p.w = pk2(h[6], h[7]);
        Af[job] = p;
    }
}

// fused concat -> padded bf16 [512][1120]
__global__ void k_fused(const float* __restrict__ feats, const float* __restrict__ ge,
                        const float* __restrict__ ae, const float* __restrict__ gcn,
                        unsigned short* __restrict__ fused)
{
    int i = blockIdx.x * 256 + threadIdx.x;
    int b = i / FP, c = i - b * FP;
    float v = 0.f;
    if (c < 512) v = feats[(long)b * 512 + c];
    else if (c < 576) v = ge[(long)b * 64 + (c - 512)];
    else if (c < 586) v = ae[(long)b * 10 + (c - 576)];
    else if (c < 1098) v = gcn[(long)b * 512 + (c - 586)];
    fused[i] = f2bf(v);
}

__device__ __forceinline__ float sigf(float x) { return 1.f / (1.f + __expf(-x)); }

__global__ __launch_bounds__(256)
void lstm_step2(const float* __restrict__ xWih,
                const float4* __restrict__ W4,
                const float* __restrict__ hPrev, const float* __restrict__ cPrev,
                float* __restrict__ hNext, float* __restrict__ cNext,
                unsigned short* __restrict__ sfb, int t)
{
    __shared__ float hlds[512 * 17];
    __shared__ float4 pex[256];
    const int tid = threadIdx.x;
    const float4* hp4 = (const float4*)hPrev;
#pragma unroll
    for (int l = 0; l < 8; ++l) {
        int i4 = tid + l * 256;
        int bb = i4 >> 7, hq = i4 & 127;
        float4 h4 = hp4[i4];
        int hh0 = hq * 4;
        hlds[(hh0 + 0) * 17 + bb] = h4.x;
        hlds[(hh0 + 1) * 17 + bb] = h4.y;
        hlds[(hh0 + 2) * 17 + bb] = h4.z;
        hlds[(hh0 + 3) * 17 + bb] = h4.w;
    }
    __syncthreads();
    const int b = tid & 15, j2 = (tid >> 4) & 1, ks = tid >> 5;
    const int jh = blockIdx.x * 2 + j2;
    float ai = 0.f, af = 0.f, ag = 0.f, ao = 0.f;
    const float4* wcol = W4 + jh;
    int hh = ks * 64;
#pragma unroll 4
    for (int r = 0; r < 64; ++r, ++hh) {
        float4 w = wcol[(long)hh * 512];
        float hp = hlds[hh * 17 + b];
        ai = fmaf(w.x, hp, ai);
        af = fmaf(w.y, hp, af);
        ag = fmaf(w.z, hp, ag);
        ao = fmaf(w.w, hp, ao);
    }
    pex[tid] = make_float4(ai, af, ag, ao);
    __syncthreads();
    if (tid < 32) {
        int fb = tid & 15, fj = tid >> 4;
        float gi = 0.f, gf = 0.f, gg = 0.f, go = 0.f;
#pragma unroll
        for (int k = 0; k < 8; ++k) {
            float4 p = pex[k * 32 + fj * 16 + fb];
            gi += p.x; gf += p.y; gg += p.z; go += p.w;
        }
        int jhf = blockIdx.x * 2 + fj;
        const float* xw = xWih + (long)(fb * T + t) * 2048;
        gi += xw[jhf]; gf += xw[512 + jhf]; gg += xw[1024 + jhf]; go += xw[1536 + jhf];
        float cp = cPrev[fb * 512 + jhf];
        float cn = sigf(gf) * cp + sigf(gi) * tanhf(gg);
        float hn = sigf(go) * tanhf(cn);
        cNext[fb * 512 + jhf] = cn;
        hNext[fb * 512 + jhf] = hn;
        sfb[(long)(fb * T + t) * 512 + jhf] = f2bf(hn);
    }
}

// final heads from hd = [ah | ch] fp32 [512][256]
__global__ void k_heads(const float* __restrict__ hd,
                        const float* __restrict__ Wa2, const float* __restrict__ ba2,
                        const float* __restrict__ Wc2, const float* __restrict__ bc2,
                        float* __restrict__ out)
{
    int row = blockIdx.x * 16 + (threadIdx.x >> 4);
    int slot = threadIdx.x & 15;
    if (slot < 6) {
        const float4* h4 = (const float4*)(hd + (long)row * 256);
        const float4* w4 = (const float4*)(Wa2 + slot * 128);
        float s = 0.f;
#pragma unroll
        for (int k = 0; k < 32; ++k) {
            float4 h = h4[k], w = w4[k];
            s += h.x * w.x + h.y * w.y + h.z * w.z + h.w * w.w;
        }
        out[row * 6 + slot] = fmaxf(s + ba2[slot], 0.f);
    } else if (slot == 6) {
        const float4* h4 = (const float4*)(hd + (long)row * 256 + 128);
        const float4* w4 = (const float4*)(Wc2);
        float s = 0.f;
#pragma unroll
        for (int k = 0; k < 32; ++k) {
            float4 h = h4[k], w = w4[k];
            s += h.x * w.x + h.y * w.y + h.z * w.z + h.w * w.w;
        }
        out[3072 + row] = fmaxf(s + bc2[0], 0.f);
    }
}

__global__ void k_copy_hc(const float* __restrict__ h, const float* __restrict__ c,
                          float* __restrict__ out)
{
    int i = blockIdx.x * 256 + threadIdx.x;
    out[3584 + i] = h[i];
    out[11776 + i] = c[i];
}

// ---------------- host ----------------
static inline void mg(hipStream_t st, const unsigned short* A, int lda,
                      const unsigned short* B, int ldb,
                      float* Cf, unsigned short* Cb, int ldc,
                      const float* bias, int M, int N, int K, bool relu, bool bf16out)
{
    dim3 g(N / 64, M / 64), blk(256);
    if (bf16out) {
        if (relu) hipLaunchKernelGGL((mgemm<true, 1>), g, blk, 0, st, A, lda, B, ldb, Cf, Cb, ldc, bias, K);
        else      hipLaunchKernelGGL((mgemm<false, 1>), g, blk, 0, st, A, lda, B, ldb, Cf, Cb, ldc, bias, K);
    } else {
        if (relu) hipLaunchKernelGGL((mgemm<true, 0>), g, blk, 0, st, A, lda, B, ldb, Cf, Cb, ldc, bias, K);
        else      hipLaunchKernelGGL((mgemm<false, 0>), g, blk, 0, st, A, lda, B, ldb, Cf, Cb, ldc, bias, K);
    }
}
static inline void g32(hipStream_t st, const float* A, int lda, const float* B, int ldb,
                       float* C, int ldc, const float* bias, int M, int N, int K, bool relu)
{
    dim3 g((N + 63) / 64, (M + 31) / 32), blk(128);
    if (relu) hipLaunchKernelGGL((gemm32<true>), g, blk, 0, st, A, lda, B, ldb, C, ldc, bias, M, N, K);
    else      hipLaunchKernelGGL((gemm32<false>), g, blk, 0, st, A, lda, B, ldb, C, ldc, bias, M, N, K);
}
static inline void gnt(hipStream_t st, const float* A, int lda, const float* B, int ldb,
                       float* C, int ldc, const float* bias, int M, int N, int K, bool relu)
{
    dim3 g((N + BN - 1) / BN, (M + BM - 1) / BM), blk(256);
    if (relu) hipLaunchKernelGGL((gemm_nt<true>), g, blk, 0, st, A, lda, B, ldb, C, ldc, bias, M, N, K);
    else      hipLaunchKernelGGL((gemm_nt<false>), g, blk, 0, st, A, lda, B, ldb, C, ldc, bias, M, N, K);
}

extern "C" void kernel_launch(void* const* d_in, const int* in_sizes, int n_in,
                              void* d_out, int out_size, void* d_ws, size_t ws_size,
                              hipStream_t stream)
{
    const float* target = (const float*)d_in[0];
    const float* input_ = (const float*)d_in[1];
    const float* aprob  = (const float*)d_in[2];
    const float* Adj    = (const float*)d_in[3];
    const float* aglove = (const float*)d_in[4];
    const float* Wword  = (const float*)d_in[5];
    const float* bword  = (const float*)d_in[6];
    const float* Wg     = (const float*)d_in[7];
    const float* bg     = (const float*)d_in[8];
    const float* Wa     = (const float*)d_in[9];
    const float* ba     = (const float*)d_in[10];
    const float* W0     = (const float*)d_in[11];
    const float* W1     = (const float*)d_in[12];
    const float* W2     = (const float*)d_in[13];
    const float* Wfm    = (const float*)d_in[14];
    const float* bfm    = (const float*)d_in[15];
    const float* Wf     = (const float*)d_in[16];
    const float* bf     = (const float*)d_in[17];
    const float* Wih    = (const float*)d_in[18];
    const float* Whh    = (const float*)d_in[19];
    const float* bih    = (const float*)d_in[20];
    const float* bhh    = (const float*)d_in[21];
    const float* Wa1    = (const float*)d_in[22];
    const float* ba1    = (const float*)d_in[23];
    const float* Wa2    = (const float*)d_in[24];
    const float* ba2    = (const float*)d_in[25];
    const float* Wc1    = (const float*)d_in[26];
    const float* bc1    = (const float*)d_in[27];
    const float* Wc2    = (const float*)d_in[28];
    const float* bc2    = (const float*)d_in[29];

    float* ws = (float*)d_ws;
    float* out = (float*)d_out;

    size_t off = 0;
    auto alloc = [&](size_t n) { size_t r = off; off += (n + 255) & ~(size_t)255; return r; };
    float* glove_e = ws + alloc(512 * 64);
    float* act_e   = ws + alloc(512 * 10);
    float* u       = ws + alloc(512 * 256);
    float* word    = ws + alloc(100 * 64);
    float* Aw      = ws + alloc(100 * 64);
    float* rowsum  = ws + alloc(128);
    float* v       = ws + alloc(100 * 256);
    float* gcn_e   = ws + alloc(512 * 512);
    float* bsum    = ws + alloc(2048);
    float* bhd     = ws + alloc(256);
    float* xWih    = ws + alloc((size_t)512 * 2048);
    float* WhhT2   = ws + alloc((size_t)512 * 2048);
    float* hA      = ws + alloc(BSZ * Hh);
    float* cA      = ws + alloc(BSZ * Hh);
    float* hB      = ws + alloc(BSZ * Hh);
    float* cB      = ws + alloc(BSZ * Hh);
    float* hd      = ws + alloc(512 * 256);
    float* W1frag  = ws + alloc(32768);
    float* Afrag   = ws + alloc(7168);
    // bf16 buffers (allocated in float units, /2)
    unsigned short* x3b     = (unsigned short*)(ws + alloc(512 * 128 / 2));
    unsigned short* fusedb  = (unsigned short*)(ws + alloc((size_t)512 * FP / 2));
    unsigned short* WfPb    = (unsigned short*)(ws + alloc((size_t)512 * FP / 2));
    unsigned short* outfb   = (unsigned short*)(ws + alloc(512 * 512 / 2));
    unsigned short* Wihb    = (unsigned short*)(ws + alloc((size_t)2048 * 512 / 2));
    unsigned short* Whdb    = (unsigned short*)(ws + alloc(256 * 512 / 2));
    unsigned short* Wgb     = (unsigned short*)(ws + alloc(64 * 320 / 2));
    unsigned short* W0ab    = (unsigned short*)(ws + alloc(256 * 512 / 2));
    unsigned short* Wfmb    = (unsigned short*)(ws + alloc(512 * 128 / 2));
    unsigned short* tgtb    = (unsigned short*)(ws + alloc(512 * 320 / 2));
    unsigned short* featsb  = (unsigned short*)(ws + alloc(512 * 512 / 2));
    unsigned short* sfb     = (unsigned short*)(ws + alloc(512 * 512 / 2));
    (void)ws_size; (void)in_sizes; (void)n_in; (void)out_size;

    const float* feats = input_; // [512,512]

    // --- preprocessing: all conversions/transposes/zeros in one launch ---
    hipLaunchKernelGGL(k_prep, dim3(13632), dim3(256), 0, stream,
                       Whh, WhhT2, Wf, WfPb, Wih, Wihb, Wa1, Wc1, Whdb, ba1, bc1, bhd,
                       Wg, Wgb, W0, W0ab, Wfm, Wfmb, target, tgtb, feats, featsb,
                       hA, bih, bhh, bsum, W1, (uint4*)W1frag, Adj, (uint4*)Afrag);

    // --- tiny fp32 GEMMs ---
    g32(stream, aglove, GLOVE, Wword, GLOVE, word, 64, bword, 100, 64, GLOVE, false);
    hipLaunchKernelGGL(k_aw_rowsum, dim3(26), dim3(256), 0, stream, Adj, word, Aw, rowsum);
    g32(stream, Aw, 64, W0 + 512, 576, v, 256, nullptr, 100, 256, 64, false);
    gnt(stream, aprob, ASPACE, Wa, ASPACE, act_e, 10, ba, 512, 10, ASPACE, true);

    // --- MFMA GEMMs: embeddings ---
    mg(stream, tgtb, 320, Wgb, 320, glove_e, nullptr, 64, bg, 512, 64, 320, true, false);
    mg(stream, featsb, 512, W0ab, 512, u, nullptr, 256, nullptr, 512, 256, 512, false, false);

    // --- fused GCN middle (MFMA) ---
    hipLaunchKernelGGL(gcn_fused, dim3(Bt), dim3(256), 0, stream,
                       u, v, rowsum, Adj, (const bf16x8*)W1frag, (const bf16x8*)Afrag, W2, x3b);
    mg(stream, x3b, 128, Wfmb, 128, gcn_e, nullptr, 512, bfm, 512, 512, 128, false, false);

    // --- fuse + trunk ---
    hipLaunchKernelGGL(k_fused, dim3(512 * FP / 256), dim3(256), 0, stream,
                       feats, glove_e, act_e, gcn_e, fusedb);
    mg(stream, fusedb, FP, WfPb, FP, nullptr, outfb, 512, bf, 512, 512, FP, true, true);
    mg(stream, outfb, 512, Wihb, 512, xWih, nullptr, 2048, bsum, 512, 2048, 512, false, false);

    // --- LSTM recurrence (fp32) ---
    for (int t = 0; t < T; ++t) {
        const float* hp = (t & 1) ? hB : hA;
        const float* cp = (t & 1) ? cB : cA;
        float* hn = (t & 1) ? hA : hB;
        float* cn = (t & 1) ? cA : cB;
        hipLaunchKernelGGL(lstm_step2, dim3(256), dim3(256), 0, stream,
                           xWih, (const float4*)WhhT2, hp, cp, hn, cn, sfb, t);
    }
    // t=31 odd -> final state in hA/cA

    // --- heads: hd = relu(sf @ [Wa1|Wc1]^T + bhd), then tiny finals ---
    mg(stream, sfb, 512, Whdb, 512, hd, nullptr, 256, bhd, 512, 256, 512, true, false);
    hipLaunchKernelGGL(k_heads, dim3(32), dim3(256), 0, stream, hd, Wa2, ba2, Wc2, bc2, out);
    hipLaunchKernelGGL(k_copy_hc, dim3(32), dim3(256), 0, stream, hA, cA, out);
}

// Round 7
// 316.950 us; speedup vs baseline: 5.6738x; 1.1720x over previous
//
#include <hip/hip_runtime.h>
#include <cmath>

// ---------------- problem constants ----------------
constexpr int BSZ = 16, T = 32, NOBJ = 100;
constexpr int GLOVE = 300, GEMB = 64, ADIM = 10, GCN_DIM = 512, Hh = 512, ASPACE = 6, RES = 512;
constexpr int Bt = BSZ * T;          // 512
constexpr int FUSED_IN = RES + GEMB + ADIM + GCN_DIM; // 1098
constexpr int FP = 1120;             // padded fused width

typedef __attribute__((ext_vector_type(8))) short bf16x8;
typedef __attribute__((ext_vector_type(4))) float f32x4;

__device__ __forceinline__ unsigned short f2bf(float f) {
    unsigned u = __float_as_uint(f);
    return (unsigned short)((u + 0x7FFFu + ((u >> 16) & 1u)) >> 16);
}
__device__ __forceinline__ unsigned pk2(float a, float b) {
    return (unsigned)f2bf(a) | ((unsigned)f2bf(b) << 16);
}
__device__ __forceinline__ float sigf(float x) { return 1.f / (1.f + __expf(-x)); }

// ---------------- mgemm: C = A @ B^T (+bias)(relu), bf16 in, fp32 acc ----------------
// No LDS, no syncs. 4 waves; wave w: rows [by*64+w*16,+16) x cols [bx*64,+64).
// M%64==0, N%64==0, K%32==0, lda/ldb%8==0.
template<bool RELU, int OMODE>  // OMODE: 0=fp32 out, 1=bf16 out
__global__ __launch_bounds__(256)
void mgemm(const unsigned short* __restrict__ A, int lda,
           const unsigned short* __restrict__ B, int ldb,
           float* __restrict__ Cf, unsigned short* __restrict__ Cb, int ldc,
           const float* __restrict__ bias, int K)
{
    const int tid = threadIdx.x;
    const int l = tid & 63, wv = tid >> 6;
    const int m0 = blockIdx.y * 64 + wv * 16;
    const int n0 = blockIdx.x * 64;
    const int lr = l & 15, kg = l >> 4;
    const unsigned short* ap = A + (long)(m0 + lr) * lda + kg * 8;
    const unsigned short* bp = B + (long)(n0 + lr) * ldb + kg * 8;
    f32x4 acc0 = (f32x4){0.f, 0.f, 0.f, 0.f};
    f32x4 acc1 = acc0, acc2 = acc0, acc3 = acc0;
    for (int k0 = 0; k0 < K; k0 += 32) {
        bf16x8 a  = *(const bf16x8*)(ap + k0);
        bf16x8 b0 = *(const bf16x8*)(bp + k0);
        bf16x8 b1 = *(const bf16x8*)(bp + 16 * ldb + k0);
        bf16x8 b2 = *(const bf16x8*)(bp + 32 * ldb + k0);
        bf16x8 b3 = *(const bf16x8*)(bp + 48 * ldb + k0);
        acc0 = __builtin_amdgcn_mfma_f32_16x16x32_bf16(a, b0, acc0, 0, 0, 0);
        acc1 = __builtin_amdgcn_mfma_f32_16x16x32_bf16(a, b1, acc1, 0, 0, 0);
        acc2 = __builtin_amdgcn_mfma_f32_16x16x32_bf16(a, b2, acc2, 0, 0, 0);
        acc3 = __builtin_amdgcn_mfma_f32_16x16x32_bf16(a, b3, acc3, 0, 0, 0);
    }
    f32x4 av[4] = {acc0, acc1, acc2, acc3};
#pragma unroll
    for (int nf = 0; nf < 4; ++nf) {
        int n = n0 + nf * 16 + lr;
        float bs = bias ? bias[n] : 0.f;
#pragma unroll
        for (int r = 0; r < 4; ++r) {
            float val = av[nf][r] + bs;
            if (RELU) val = fmaxf(val, 0.f);
            long idx = (long)(m0 + kg * 4 + r) * ldc + n;
            if (OMODE == 0) Cf[idx] = val;
            else            Cb[idx] = f2bf(val);
        }
    }
}

// ---------------- fp32 GEMM for tiny ragged cases (word, v) ----------------
template<bool RELU>
__global__ __launch_bounds__(128)
void gemm32(const float* __restrict__ A, int lda,
            const float* __restrict__ B, int ldb,
            float* __restrict__ C, int ldc,
            const float* __restrict__ bias, int M, int N, int K)
{
    __shared__ float As[32][36];
    __shared__ float Bs[32][68];
    const int tid = threadIdx.x;
    const int m0 = blockIdx.y * 32, n0 = blockIdx.x * 64;
    const int mi = tid >> 4, ni = tid & 15;
    float acc[4][4] = {};
    for (int k0 = 0; k0 < K; k0 += 32) {
        __syncthreads();
#pragma unroll
        for (int l = 0; l < 2; ++l) {
            int e = tid + l * 128;
            int row = e >> 3, kq = (e & 7) << 2;
            float4 va = make_float4(0.f, 0.f, 0.f, 0.f);
            if (m0 + row < M && k0 + kq < K)
                va = *(const float4*)&A[(long)(m0 + row) * lda + k0 + kq];
            As[kq + 0][row] = va.x; As[kq + 1][row] = va.y;
            As[kq + 2][row] = va.z; As[kq + 3][row] = va.w;
        }
#pragma unroll
        for (int l = 0; l < 4; ++l) {
            int e = tid + l * 128;
            int row = e >> 3, kq = (e & 7) << 2;
            float4 vb = make_float4(0.f, 0.f, 0.f, 0.f);
            if (n0 + row < N && k0 + kq < K)
                vb = *(const float4*)&B[(long)(n0 + row) * ldb + k0 + kq];
            Bs[kq + 0][row] = vb.x; Bs[kq + 1][row] = vb.y;
            Bs[kq + 2][row] = vb.z; Bs[kq + 3][row] = vb.w;
        }
        __syncthreads();
#pragma unroll
        for (int k = 0; k < 32; ++k) {
            float4 a4 = *(const float4*)&As[k][4 * mi];
            float4 b4 = *(const float4*)&Bs[k][4 * ni];
            acc[0][0] = fmaf(a4.x, b4.x, acc[0][0]); acc[0][1] = fmaf(a4.x, b4.y, acc[0][1]);
            acc[0][2] = fmaf(a4.x, b4.z, acc[0][2]); acc[0][3] = fmaf(a4.x, b4.w, acc[0][3]);
            acc[1][0] = fmaf(a4.y, b4.x, acc[1][0]); acc[1][1] = fmaf(a4.y, b4.y, acc[1][1]);
            acc[1][2] = fmaf(a4.y, b4.z, acc[1][2]); acc[1][3] = fmaf(a4.y, b4.w, acc[1][3]);
            acc[2][0] = fmaf(a4.z, b4.x, acc[2][0]); acc[2][1] = fmaf(a4.z, b4.y, acc[2][1]);
            acc[2][2] = fmaf(a4.z, b4.z, acc[2][2]); acc[2][3] = fmaf(a4.z, b4.w, acc[2][3]);
            acc[3][0] = fmaf(a4.w, b4.x, acc[3][0]); acc[3][1] = fmaf(a4.w, b4.y, acc[3][1]);
            acc[3][2] = fmaf(a4.w, b4.z, acc[3][2]); acc[3][3] = fmaf(a4.w, b4.w, acc[3][3]);
        }
    }
    const int n = n0 + 4 * ni;
    if (n >= N) return;
    float4 bv = make_float4(0.f, 0.f, 0.f, 0.f);
    if (bias) bv = *(const float4*)&bias[n];
#pragma unroll
    for (int r = 0; r < 4; ++r) {
        int m = m0 + 4 * mi + r;
        if (m >= M) continue;
        float4 v;
        v.x = acc[r][0] + bv.x; v.y = acc[r][1] + bv.y;
        v.z = acc[r][2] + bv.z; v.w = acc[r][3] + bv.w;
        if (RELU) {
            v.x = fmaxf(v.x, 0.f); v.y = fmaxf(v.y, 0.f);
            v.z = fmaxf(v.z, 0.f); v.w = fmaxf(v.w, 0.f);
        }
        *(float4*)&C[(long)m * ldc + n] = v;
    }
}

// ---------------- fused GCN middle, MFMA + v-prefetch double-buffer ----------------
constexpr int ZLD = 152;   // Z1T stride in shorts (304 B: 16B-aligned, ~2-way banks)

__global__ __launch_bounds__(256, 2)
void gcn_fused(const float* __restrict__ u,      // [512,256]
               const float* __restrict__ v,      // [100,256]
               const float* __restrict__ rowsum, // [100]
               const float* __restrict__ Aglob,  // [100,100] fp32
               const bf16x8* __restrict__ W1f,   // [16jt][8kt][64lane] frags
               const bf16x8* __restrict__ Af,    // [7mt][4kt][64lane] frags
               const float* __restrict__ w2,     // [256]
               unsigned short* __restrict__ x3b) // [512,128] bf16, cols >=100 zero
{
    __shared__ unsigned short X1s[2][112 * 40];  // double-buffered [n][k-tile 32 + pad]
    __shared__ unsigned short Z1Ts[128 * ZLD];
    __shared__ float u_lds[256];
    __shared__ float rs_lds[112];
    __shared__ float w2l[256];
    __shared__ float spart[4][112];
    __shared__ float sl[112];

    const int b = blockIdx.x, tid = threadIdx.x;
    const int l = tid & 63, wv = tid >> 6;
    const int lrow = l & 15, kg = l >> 4;

    u_lds[tid] = u[(long)b * 256 + tid];
    w2l[tid] = w2[tid];
    if (tid < 112) rs_lds[tid] = (tid < 100) ? rowsum[tid] : 0.f;
    if (tid < 128) {
        uint4 z = make_uint4(0, 0, 0, 0);
        *(uint4*)&Z1Ts[tid * ZLD + 112] = z;
        *(uint4*)&Z1Ts[tid * ZLD + 120] = z;
    }
    if (tid < 28) x3b[(long)b * 128 + 100 + tid] = 0;
    __syncthreads();

    // staging lane identity
    const int sn = tid >> 1;            // 0..111 (for tid<224)
    const int kh = (tid & 1) << 4;      // 0 or 16
    const int kq = kh >> 2;             // 0 or 4
    const bool gen = (tid < 224) && (sn < 100);
    const float4* vrow = gen ? ((const float4*)v + sn * 64) : nullptr;
    const float rsn = (tid < 224) ? rs_lds[sn] : 0.f;

    float sacc[7][4];
#pragma unroll
    for (int mt = 0; mt < 7; ++mt)
#pragma unroll
        for (int r = 0; r < 4; ++r) sacc[mt][r] = 0.f;

    for (int half = 0; half < 2; ++half) {
        f32x4 acc1[7][2];
#pragma unroll
        for (int mt = 0; mt < 7; ++mt)
#pragma unroll
            for (int jtl = 0; jtl < 2; ++jtl) acc1[mt][jtl] = (f32x4){0.f, 0.f, 0.f, 0.f};

        // prefetch kt=0 v-tile
        float4 q0, q1, q2, q3;
        if (gen) { q0 = vrow[kq]; q1 = vrow[kq + 1]; q2 = vrow[kq + 2]; q3 = vrow[kq + 3]; }

        int buf = 0;
        for (int kt = 0; kt < 8; ++kt) {
            // pack current tile into X1s[buf]
            if (tid < 224) {
                int kb = kt * 32 + kh;
                uint4 p0 = make_uint4(0, 0, 0, 0), p1 = make_uint4(0, 0, 0, 0);
                if (gen) {
                    float4 u0 = *(const float4*)&u_lds[kb];
                    float4 u1 = *(const float4*)&u_lds[kb + 4];
                    float4 u2 = *(const float4*)&u_lds[kb + 8];
                    float4 u3 = *(const float4*)&u_lds[kb + 12];
                    float x0 = fmaxf(fmaf(rsn, u0.x, q0.x), 0.f), x1 = fmaxf(fmaf(rsn, u0.y, q0.y), 0.f);
                    float x2 = fmaxf(fmaf(rsn, u0.z, q0.z), 0.f), x3v = fmaxf(fmaf(rsn, u0.w, q0.w), 0.f);
                    float x4 = fmaxf(fmaf(rsn, u1.x, q1.x), 0.f), x5 = fmaxf(fmaf(rsn, u1.y, q1.y), 0.f);
                    float x6 = fmaxf(fmaf(rsn, u1.z, q1.z), 0.f), x7 = fmaxf(fmaf(rsn, u1.w, q1.w), 0.f);
                    float x8 = fmaxf(fmaf(rsn, u2.x, q2.x), 0.f), x9 = fmaxf(fmaf(rsn, u2.y, q2.y), 0.f);
                    float xa = fmaxf(fmaf(rsn, u2.z, q2.z), 0.f), xb = fmaxf(fmaf(rsn, u2.w, q2.w), 0.f);
                    float xc = fmaxf(fmaf(rsn, u3.x, q3.x), 0.f), xd = fmaxf(fmaf(rsn, u3.y, q3.y), 0.f);
                    float xe = fmaxf(fmaf(rsn, u3.z, q3.z), 0.f), xf = fmaxf(fmaf(rsn, u3.w, q3.w), 0.f);
                    p0 = make_uint4(pk2(x0, x1), pk2(x2, x3v), pk2(x4, x5), pk2(x6, x7));
                    p1 = make_uint4(pk2(x8, x9), pk2(xa, xb), pk2(xc, xd), pk2(xe, xf));
                }
                *(uint4*)&X1s[buf][sn * 40 + kh] = p0;
                *(uint4*)&X1s[buf][sn * 40 + kh + 8] = p1;
            }
            // prefetch kt+1 (latency hidden under barrier + MFMA)
            float4 n0q, n1q, n2q, n3q;
            if (kt < 7 && gen) {
                int base = (kt + 1) * 8 + kq;
                n0q = vrow[base]; n1q = vrow[base + 1]; n2q = vrow[base + 2]; n3q = vrow[base + 3];
            }
            __syncthreads();
            bf16x8 af[7];
#pragma unroll
            for (int mt = 0; mt < 7; ++mt)
                af[mt] = *(const bf16x8*)&X1s[buf][(mt * 16 + lrow) * 40 + kg * 8];
#pragma unroll
            for (int jtl = 0; jtl < 2; ++jtl) {
                int jt = half * 8 + wv * 2 + jtl;
                bf16x8 bfr = W1f[(jt * 8 + kt) * 64 + l];
#pragma unroll
                for (int mt = 0; mt < 7; ++mt)
                    acc1[mt][jtl] = __builtin_amdgcn_mfma_f32_16x16x32_bf16(af[mt], bfr, acc1[mt][jtl], 0, 0, 0);
            }
            q0 = n0q; q1 = n1q; q2 = n2q; q3 = n3q;
            buf ^= 1;
        }

        // write Z1T (wave-private rows), bf16
#pragma unroll
        for (int mt = 0; mt < 7; ++mt)
#pragma unroll
            for (int jtl = 0; jtl < 2; ++jtl) {
                int jloc = (wv * 2 + jtl) * 16 + lrow;
                f32x4 a = acc1[mt][jtl];
                uint2 zz;
                zz.x = pk2(a[0], a[1]);
                zz.y = pk2(a[2], a[3]);
                *(uint2*)&Z1Ts[jloc * ZLD + mt * 16 + kg * 4] = zz;
            }

        // phase 2: X2 = A @ Z1 (same-wave read of just-written rows)
        bf16x8 bz[2][4];
#pragma unroll
        for (int jtl = 0; jtl < 2; ++jtl)
#pragma unroll
            for (int k2 = 0; k2 < 4; ++k2)
                bz[jtl][k2] = *(const bf16x8*)&Z1Ts[((wv * 2 + jtl) * 16 + lrow) * ZLD + k2 * 32 + kg * 8];
#pragma unroll
        for (int mt = 0; mt < 7; ++mt) {
            bf16x8 aA[4];
#pragma unroll
            for (int k2 = 0; k2 < 4; ++k2) aA[k2] = Af[(mt * 4 + k2) * 64 + l];
#pragma unroll
            for (int jtl = 0; jtl < 2; ++jtl) {
                f32x4 p = (f32x4){0.f, 0.f, 0.f, 0.f};
#pragma unroll
                for (int k2 = 0; k2 < 4; ++k2)
                    p = __builtin_amdgcn_mfma_f32_16x16x32_bf16(aA[k2], bz[jtl][k2], p, 0, 0, 0);
                float w2j = w2l[half * 128 + (wv * 2 + jtl) * 16 + lrow];
#pragma unroll
                for (int r = 0; r < 4; ++r)
                    sacc[mt][r] = fmaf(fmaxf(p[r], 0.f), w2j, sacc[mt][r]);
            }
        }
    }

    // reduce sacc over j (low 4 lane bits) -> spart
#pragma unroll
    for (int mt = 0; mt < 7; ++mt) {
        float s0 = sacc[mt][0], s1 = sacc[mt][1], s2 = sacc[mt][2], s3 = sacc[mt][3];
#pragma unroll
        for (int off = 1; off < 16; off <<= 1) {
            s0 += __shfl_xor(s0, off);
            s1 += __shfl_xor(s1, off);
            s2 += __shfl_xor(s2, off);
            s3 += __shfl_xor(s3, off);
        }
        if (lrow == 0) {
            int m = mt * 16 + kg * 4;
            spart[wv][m + 0] = s0; spart[wv][m + 1] = s1;
            spart[wv][m + 2] = s2; spart[wv][m + 3] = s3;
        }
    }
    __syncthreads();
    if (tid < 112)
        sl[tid] = spart[0][tid] + spart[1][tid] + spart[2][tid] + spart[3][tid];
    __syncthreads();

    // phase 3: x3[b,n] = relu(sum_m A[n,m]*s[m])
    float sv0 = (l < 100) ? sl[l] : 0.f;
    float sv1 = (l + 64 < 100) ? sl[l + 64] : 0.f;
#pragma unroll 5
    for (int i = 0; i < 25; ++i) {
        int n = i * 4 + wv;
        float a0 = (l < 100) ? Aglob[n * 100 + l] : 0.f;
        float a1 = (l + 64 < 100) ? Aglob[n * 100 + l + 64] : 0.f;
        float p = a0 * sv0 + a1 * sv1;
#pragma unroll
        for (int off = 32; off; off >>= 1) p += __shfl_xor(p, off);
        if (l == 0) x3b[(long)b * 128 + n] = f2bf(fmaxf(p, 0.f));
    }
}

// ---------------- LSTM step via MFMA ----------------
// 32 blocks x 256 thr (4 waves). Block bid owns jh-slice [bid*16,+16); wave g = gate type.
// Whhf frag-major bf16: Whhf[(jt*16+kt)*64+l], jt = g*32+bid (n-tile over j = g*512+jh).
__global__ __launch_bounds__(256)
void lstm_mf(const float* __restrict__ xWih,            // [512][2048], rows b*T+t
             const bf16x8* __restrict__ Whhf,
             const unsigned short* __restrict__ hPrev,  // [16][512] bf16
             unsigned short* __restrict__ hNext,        // [16][512] bf16
             float* __restrict__ cBuf,                  // [16][512] fp32 (block-private slice)
             float* __restrict__ hFin,                  // [16][512] fp32
             unsigned short* __restrict__ sfb, int t)
{
    __shared__ float gl[4][16][17];
    const int tid = threadIdx.x;
    const int l = tid & 63, g = tid >> 6;
    const int bid = blockIdx.x;
    const int jt = g * 32 + bid;
    const int lr = l & 15, kg = l >> 4;
    const unsigned short* hp = hPrev + lr * 512 + kg * 8;
    const bf16x8* wp = Whhf + (size_t)jt * 16 * 64 + l;
    f32x4 acc = (f32x4){0.f, 0.f, 0.f, 0.f};
#pragma unroll
    for (int kt = 0; kt < 16; ++kt) {
        bf16x8 a = *(const bf16x8*)(hp + kt * 32);
        acc = __builtin_amdgcn_mfma_f32_16x16x32_bf16(a, wp[kt * 64], acc, 0, 0, 0);
    }
#pragma unroll
    for (int r = 0; r < 4; ++r) gl[g][kg * 4 + r][lr] = acc[r];
    __syncthreads();
    const int b = tid >> 4, jl = tid & 15;
    const int jh = bid * 16 + jl;
    const float* xw = xWih + (size_t)(b * T + t) * 2048;
    float gi = gl[0][b][jl] + xw[jh];
    float gf = gl[1][b][jl] + xw[512 + jh];
    float gg = gl[2][b][jl] + xw[1024 + jh];
    float go = gl[3][b][jl] + xw[1536 + jh];
    float cp = cBuf[b * 512 + jh];
    float cn = sigf(gf) * cp + sigf(gi) * tanhf(gg);
    float hn = sigf(go) * tanhf(cn);
    cBuf[b * 512 + jh] = cn;
    hNext[b * 512 + jh] = f2bf(hn);
    hFin[b * 512 + jh] = hn;
    sfb[(size_t)(b * T + t) * 512 + jh] = f2bf(hn);
}

// ---------------- glue kernels ----------------
__global__ void k_aw_rowsum(const float* __restrict__ A, const float* __restrict__ word,
                            float* __restrict__ Aw, float* __restrict__ rowsum)
{
    int i = blockIdx.x * 256 + threadIdx.x;
    if (i < 6400) {
        int n = i / 64, k = i % 64;
        float s = 0.f;
        for (int m = 0; m < 100; ++m) s += A[n * 100 + m] * word[m * 64 + k];
        Aw[i] = s;
    } else if (i < 6500) {
        int n = i - 6400;
        float s = 0.f;
        for (int m = 0; m < 100; ++m) s += A[n * 100 + m];
        rowsum[n] = s;
    }
}

// preprocessing: all conversions/layouts/zeros. Segment boundaries (blocks of 256):
//  [0,512)        Whhf bf16 frag-major (2048 j x 512 k)
//  [512,2752)     WfPb [512][1120] pad bf16
//  [2752,6848)    Wihb [2048][512] bf16
//  [6848,7360)    Whdb [256][512] = Wa1|Wc1 bf16
//  [7360,7361)    bhd = ba1|bc1
//  [7361,7441)    Wgb [64][320] pad bf16
//  [7441,7953)    W0ab [256][512] bf16
//  [7953,8209)    Wfmb [512][128] pad bf16
//  [8209,8849)    tgtb [512][320] pad bf16
//  [8849,9873)    featsb [512][512] bf16
//  [9873,10897)   fusedb cols 0..512 = feats bf16
//  [10897,10917)  fusedb cols 576..586 = act_e (6-MAC dot + relu)
//  [10917,10961)  fusedb cols 1098..1120 = 0
//  [10961,11009)  zeros: hbA (4096 bf16) + cBuf (8192 f32)
//  [11009,11017)  bsum = bih+bhh
//  [11017,11049)  W1frag
//  [11049,11056)  Afrag
__global__ void k_prep(const float* __restrict__ Whh, uint4* __restrict__ Whhf,
                       const float* __restrict__ Wf, unsigned short* __restrict__ WfPb,
                       const float* __restrict__ Wih, unsigned short* __restrict__ Wihb,
                       const float* __restrict__ Wa1, const float* __restrict__ Wc1,
                       unsigned short* __restrict__ Whdb,
                       const float* __restrict__ ba1, const float* __restrict__ bc1,
                       float* __restrict__ bhd,
                       const float* __restrict__ Wg, unsigned short* __restrict__ Wgb,
                       const float* __restrict__ W0, unsigned short* __restrict__ W0ab,
                       const float* __restrict__ Wfm, unsigned short* __restrict__ Wfmb,
                       const float* __restrict__ target, unsigned short* __restrict__ tgtb,
                       const float* __restrict__ feats, unsigned short* __restrict__ featsb,
                       unsigned short* __restrict__ fusedb,
                       const float* __restrict__ aprob, const float* __restrict__ Wa,
                       const float* __restrict__ ba,
                       unsigned short* __restrict__ hbA, float* __restrict__ cBuf,
                       const float* __restrict__ bih, const float* __restrict__ bhh,
                       float* __restrict__ bsum,
                       const float* __restrict__ W1, uint4* __restrict__ W1f,
                       const float* __restrict__ A, uint4* __restrict__ Af)
{
    int bx = blockIdx.x, tid = threadIdx.x;
    if (bx < 512) {
        int job = bx * 256 + tid;                  // < 131072
        int jtkt = job >> 6, ll = job & 63;
        int j = (jtkt >> 4) * 16 + (ll & 15);
        int k0 = (jtkt & 15) * 32 + (ll >> 4) * 8;
        const float* src = &Whh[(long)j * 512 + k0];
        uint4 p;
        p.x = pk2(src[0], src[1]); p.y = pk2(src[2], src[3]);
        p.z = pk2(src[4], src[5]); p.w = pk2(src[6], src[7]);
        Whhf[job] = p;
    } else if (bx < 2752) {
        int i = (bx - 512) * 256 + tid;
        int r = i / FP, c = i - r * FP;
        WfPb[i] = f2bf(c < FUSED_IN ? Wf[(long)r * FUSED_IN + c] : 0.f);
    } else if (bx < 6848) {
        int i = (bx - 2752) * 256 + tid;
        Wihb[i] = f2bf(Wih[i]);
    } else if (bx < 7360) {
        int i = (bx - 6848) * 256 + tid;
        int r = i >> 9, c = i & 511;
        Whdb[i] = f2bf(r < 128 ? Wa1[r * 512 + c] : Wc1[(r - 128) * 512 + c]);
    } else if (bx < 7361) {
        bhd[tid] = (tid < 128) ? ba1[tid] : bc1[tid - 128];
    } else if (bx < 7441) {
        int i = (bx - 7361) * 256 + tid;
        int r = i / 320, c = i - r * 320;
        Wgb[i] = f2bf(c < GLOVE ? Wg[r * GLOVE + c] : 0.f);
    } else if (bx < 7953) {
        int i = (bx - 7441) * 256 + tid;
        int r = i >> 9, c = i & 511;
        W0ab[i] = f2bf(W0[(long)r * 576 + c]);
    } else if (bx < 8209) {
        int i = (bx - 7953) * 256 + tid;
        int r = i >> 7, c = i & 127;
        Wfmb[i] = f2bf(c < 100 ? Wfm[r * 100 + c] : 0.f);
    } else if (bx < 8849) {
        int i = (bx - 8209) * 256 + tid;
        int r = i / 320, c = i - r * 320;
        tgtb[i] = f2bf(c < GLOVE ? target[(long)r * GLOVE + c] : 0.f);
    } else if (bx < 9873) {
        int i = (bx - 8849) * 256 + tid;
        featsb[i] = f2bf(feats[i]);
    } else if (bx < 10897) {
        int i = (bx - 9873) * 256 + tid;           // < 262144
        int r = i >> 9, c = i & 511;
        fusedb[(long)r * FP + c] = f2bf(feats[i]);
    } else if (bx < 10917) {
        int i = (bx - 10897) * 256 + tid;          // < 5120
        int r = i / 10, c6 = i - r * 10;
        float s = ba[c6];
#pragma unroll
        for (int k = 0; k < 6; ++k) s += aprob[r * 6 + k] * Wa[c6 * 6 + k];
        fusedb[(long)r * FP + 576 + c6] = f2bf(fmaxf(s, 0.f));
    } else if (bx < 10961) {
        int i = (bx - 10917) * 256 + tid;          // < 11264
        int r = i / 22, c = 1098 + (i - r * 22);
        fusedb[(long)r * FP + c] = 0;
    } else if (bx < 11009) {
        int sub = bx - 10961;
        if (sub < 16) { int i = sub * 256 + tid; hbA[i] = 0; }
        else          { int i = (sub - 16) * 256 + tid; cBuf[i] = 0.f; }
    } else if (bx < 11017) {
        int i = (bx - 11009) * 256 + tid;
        bsum[i] = bih[i] + bhh[i];
    } else if (bx < 11049) {
        int job = (bx - 11017) * 256 + tid;        // < 8192
        int jt = job >> 9, rem = job & 511, kt = rem >> 6, lane = rem & 63;
        int j = jt * 16 + (lane & 15), k0 = kt * 32 + (lane >> 4) * 8;
        const float* src = &W1[(long)j * 256 + k0];
        uint4 p;
        p.x = pk2(src[0], src[1]); p.y = pk2(src[2], src[3]);
        p.z = pk2(src[4], src[5]); p.w = pk2(src[6], src[7]);
        W1f[job] = p;
    } else {
        int job = (bx - 11049) * 256 + tid;        // < 1792
        int mt = job >> 8, rem = job & 255, kt = rem >> 6, lane = rem & 63;
        int m = mt * 16 + (lane & 15), n0 = kt * 32 + (lane >> 4) * 8;
        float h[8];
#pragma unroll
        for (int e = 0; e < 8; ++e)
            h[e] = (m < 100 && n0 + e < 100) ? A[m * 100 + n0 + e] : 0.f;
        uint4 p;
        p.x = pk2(h[0], h[1]); p.y = pk2(h[2], h[3]);
        p.z = pk2(h[4], h[5]); p.w = pk2(h[6], h[7]);
        Af[job] = p;
    }
}

// finish: heads (blocks 0..31) + h/c copy (blocks 32..63)
__global__ void k_finish(const float* __restrict__ hd,
                         const float* __restrict__ Wa2, const float* __restrict__ ba2,
                         const float* __restrict__ Wc2, const float* __restrict__ bc2,
                         const float* __restrict__ hFin, const float* __restrict__ cBuf,
                         float* __restrict__ out)
{
    if (blockIdx.x < 32) {
        int row = blockIdx.x * 16 + (threadIdx.x >> 4);
        int slot = threadIdx.x & 15;
        if (slot < 6) {
            const float4* h4 = (const float4*)(hd + (long)row * 256);
            const float4* w4 = (const float4*)(Wa2 + slot * 128);
            float s = 0.f;
#pragma unroll
            for (int k = 0; k < 32; ++k) {
                float4 h = h4[k], w = w4[k];
                s += h.x * w.x + h.y * w.y + h.z * w.z + h.w * w.w;
            }
            out[row * 6 + slot] = fmaxf(s + ba2[slot], 0.f);
        } else if (slot == 6) {
            const float4* h4 = (const float4*)(hd + (long)row * 256 + 128);
            const float4* w4 = (const float4*)(Wc2);
            float s = 0.f;
#pragma unroll
            for (int k = 0; k < 32; ++k) {
                float4 h = h4[k], w = w4[k];
                s += h.x * w.x + h.y * w.y + h.z * w.z + h.w * w.w;
            }
            out[3072 + row] = fmaxf(s + bc2[0], 0.f);
        }
    } else {
        int i = (blockIdx.x - 32) * 256 + threadIdx.x;   // < 8192
        out[3584 + i] = hFin[i];
        out[11776 + i] = cBuf[i];
    }
}

// ---------------- host ----------------
static inline void mg(hipStream_t st, const unsigned short* A, int lda,
                      const unsigned short* B, int ldb,
                      float* Cf, unsigned short* Cb, int ldc,
                      const float* bias, int M, int N, int K, bool relu, bool bf16out)
{
    dim3 g(N / 64, M / 64), blk(256);
    if (bf16out) {
        if (relu) hipLaunchKernelGGL((mgemm<true, 1>), g, blk, 0, st, A, lda, B, ldb, Cf, Cb, ldc, bias, K);
        else      hipLaunchKernelGGL((mgemm<false, 1>), g, blk, 0, st, A, lda, B, ldb, Cf, Cb, ldc, bias, K);
    } else {
        if (relu) hipLaunchKernelGGL((mgemm<true, 0>), g, blk, 0, st, A, lda, B, ldb, Cf, Cb, ldc, bias, K);
        else      hipLaunchKernelGGL((mgemm<false, 0>), g, blk, 0, st, A, lda, B, ldb, Cf, Cb, ldc, bias, K);
    }
}
static inline void g32(hipStream_t st, const float* A, int lda, const float* B, int ldb,
                       float* C, int ldc, const float* bias, int M, int N, int K, bool relu)
{
    dim3 g((N + 63) / 64, (M + 31) / 32), blk(128);
    if (relu) hipLaunchKernelGGL((gemm32<true>), g, blk, 0, st, A, lda, B, ldb, C, ldc, bias, M, N, K);
    else      hipLaunchKernelGGL((gemm32<false>), g, blk, 0, st, A, lda, B, ldb, C, ldc, bias, M, N, K);
}

extern "C" void kernel_launch(void* const* d_in, const int* in_sizes, int n_in,
                              void* d_out, int out_size, void* d_ws, size_t ws_size,
                              hipStream_t stream)
{
    const float* target = (const float*)d_in[0];
    const float* input_ = (const float*)d_in[1];
    const float* aprob  = (const float*)d_in[2];
    const float* Adj    = (const float*)d_in[3];
    const float* aglove = (const float*)d_in[4];
    const float* Wword  = (const float*)d_in[5];
    const float* bword  = (const float*)d_in[6];
    const float* Wg     = (const float*)d_in[7];
    const float* bg     = (const float*)d_in[8];
    const float* Wa     = (const float*)d_in[9];
    const float* ba     = (const float*)d_in[10];
    const float* W0     = (const float*)d_in[11];
    const float* W1     = (const float*)d_in[12];
    const float* W2     = (const float*)d_in[13];
    const float* Wfm    = (const float*)d_in[14];
    const float* bfm    = (const float*)d_in[15];
    const float* Wf     = (const float*)d_in[16];
    const float* bf     = (const float*)d_in[17];
    const float* Wih    = (const float*)d_in[18];
    const float* Whh    = (const float*)d_in[19];
    const float* bih    = (const float*)d_in[20];
    const float* bhh    = (const float*)d_in[21];
    const float* Wa1    = (const float*)d_in[22];
    const float* ba1    = (const float*)d_in[23];
    const float* Wa2    = (const float*)d_in[24];
    const float* ba2    = (const float*)d_in[25];
    const float* Wc1    = (const float*)d_in[26];
    const float* bc1    = (const float*)d_in[27];
    const float* Wc2    = (const float*)d_in[28];
    const float* bc2    = (const float*)d_in[29];

    float* ws = (float*)d_ws;
    float* out = (float*)d_out;

    size_t off = 0;
    auto alloc = [&](size_t n) { size_t r = off; off += (n + 255) & ~(size_t)255; return r; };
    float* u       = ws + alloc(512 * 256);
    float* word    = ws + alloc(100 * 64);
    float* Aw      = ws + alloc(100 * 64);
    float* rowsum  = ws + alloc(128);
    float* v       = ws + alloc(100 * 256);
    float* bsum    = ws + alloc(2048);
    float* bhd     = ws + alloc(256);
    float* xWih    = ws + alloc((size_t)512 * 2048);
    float* hd      = ws + alloc(512 * 256);
    float* hFin    = ws + alloc(BSZ * Hh);
    float* cBuf    = ws + alloc(BSZ * Hh);
    float* W1frag  = ws + alloc(32768);
    float* Afrag   = ws + alloc(7168);
    float* Whhf    = ws + alloc((size_t)524288);   // 2 MB bf16 frags
    // bf16 buffers (alloc in float units, /2)
    unsigned short* x3b     = (unsigned short*)(ws + alloc(512 * 128 / 2));
    unsigned short* fusedb  = (unsigned short*)(ws + alloc((size_t)512 * FP / 2));
    unsigned short* WfPb    = (unsigned short*)(ws + alloc((size_t)512 * FP / 2));
    unsigned short* outfb   = (unsigned short*)(ws + alloc(512 * 512 / 2));
    unsigned short* Wihb    = (unsigned short*)(ws + alloc((size_t)2048 * 512 / 2));
    unsigned short* Whdb    = (unsigned short*)(ws + alloc(256 * 512 / 2));
    unsigned short* Wgb     = (unsigned short*)(ws + alloc(64 * 320 / 2));
    unsigned short* W0ab    = (unsigned short*)(ws + alloc(256 * 512 / 2));
    unsigned short* Wfmb    = (unsigned short*)(ws + alloc(512 * 128 / 2));
    unsigned short* tgtb    = (unsigned short*)(ws + alloc(512 * 320 / 2));
    unsigned short* featsb  = (unsigned short*)(ws + alloc(512 * 512 / 2));
    unsigned short* sfb     = (unsigned short*)(ws + alloc(512 * 512 / 2));
    unsigned short* hbA     = (unsigned short*)(ws + alloc(BSZ * Hh / 2));
    unsigned short* hbB     = (unsigned short*)(ws + alloc(BSZ * Hh / 2));
    (void)ws_size; (void)in_sizes; (void)n_in; (void)out_size;

    const float* feats = input_; // [512,512]

    // --- preprocessing: everything layout/convert/zero in one launch ---
    hipLaunchKernelGGL(k_prep, dim3(11056), dim3(256), 0, stream,
                       Whh, (uint4*)Whhf, Wf, WfPb, Wih, Wihb, Wa1, Wc1, Whdb, ba1, bc1, bhd,
                       Wg, Wgb, W0, W0ab, Wfm, Wfmb, target, tgtb, feats, featsb,
                       fusedb, aprob, Wa, ba, hbA, cBuf, bih, bhh, bsum,
                       W1, (uint4*)W1frag, Adj, (uint4*)Afrag);

    // --- word branch (tiny fp32) ---
    g32(stream, aglove, GLOVE, Wword, GLOVE, word, 64, bword, 100, 64, GLOVE, false);
    hipLaunchKernelGGL(k_aw_rowsum, dim3(26), dim3(256), 0, stream, Adj, word, Aw, rowsum);
    g32(stream, Aw, 64, W0 + 512, 576, v, 256, nullptr, 100, 256, 64, false);

    // --- MFMA GEMMs ---
    mg(stream, featsb, 512, W0ab, 512, u, nullptr, 256, nullptr, 512, 256, 512, false, false);
    mg(stream, tgtb, 320, Wgb, 320, nullptr, fusedb + 512, FP, bg, 512, 64, 320, true, true);

    // --- fused GCN middle ---
    hipLaunchKernelGGL(gcn_fused, dim3(Bt), dim3(256), 0, stream,
                       u, v, rowsum, Adj, (const bf16x8*)W1frag, (const bf16x8*)Afrag, W2, x3b);
    mg(stream, x3b, 128, Wfmb, 128, nullptr, fusedb + 586, FP, bfm, 512, 512, 128, false, true);

    // --- trunk ---
    mg(stream, fusedb, FP, WfPb, FP, nullptr, outfb, 512, bf, 512, 512, FP, true, true);
    mg(stream, outfb, 512, Wihb, 512, xWih, nullptr, 2048, bsum, 512, 2048, 512, false, false);

    // --- LSTM recurrence: 32 MFMA steps, ping-pong bf16 h ---
    for (int t = 0; t < T; ++t) {
        const unsigned short* hp = (t & 1) ? hbB : hbA;
        unsigned short* hn = (t & 1) ? hbA : hbB;
        hipLaunchKernelGGL(lstm_mf, dim3(32), dim3(256), 0, stream,
                           xWih, (const bf16x8*)Whhf, hp, hn, cBuf, hFin, sfb, t);
    }

    // --- heads ---
    mg(stream, sfb, 512, Whdb, 512, hd, nullptr, 256, bhd, 512, 256, 512, true, false);
    hipLaunchKernelGGL(k_finish, dim3(64), dim3(256), 0, stream,
                       hd, Wa2, ba2, Wc2, bc2, hFin, cBuf, out);
}